// Round 3
// baseline (1486.395 us; speedup 1.0000x reference)
//
#include <hip/hip_runtime.h>

typedef unsigned int u32;
typedef __attribute__((ext_vector_type(8))) short short8;
typedef __attribute__((ext_vector_type(4))) short short4v;
typedef __attribute__((ext_vector_type(4))) float f32x4;

__device__ __forceinline__ float lrelu(float x){ return x > 0.f ? x : 0.2f*x; }

// float atomic max via sign-split (dest init -inf)
__device__ __forceinline__ void atomicMaxF(float* a, float v){
  if (__float_as_int(v) >= 0) atomicMax((int*)a, __float_as_int(v));
  else                        atomicMin((u32*)a, __float_as_uint(v));
}

__global__ void init_ws(float* __restrict__ nf1, float* __restrict__ nf2, int n32){
  int i = blockIdx.x*blockDim.x + threadIdx.x;
  int st = gridDim.x*blockDim.x;
  for (; i < n32; i += st){ nf1[i] = 0.f; nf2[i] = -__builtin_inff(); }
}

// RNE split: x = bf16(hi) + bf16(lo) + O(2^-18 x).
struct HL { short hi, lo; };
__device__ __forceinline__ HL split1(float x){
  u32 u = __float_as_uint(x);
  u32 r = u + 0x7FFFu + ((u >> 16) & 1u);
  float l = x - __uint_as_float(r & 0xFFFF0000u);
  HL o; o.hi = (short)(r >> 16); o.lo = (short)(__float_as_uint(l) >> 16);
  return o;
}

// one-time gather of a B fragment (W row-major [K][Nout], f32) with zero-fill OOB
__device__ __forceinline__ void gatherB(const float* __restrict__ W, int K, int Nout,
                                        int kbase, int n, short8& hi, short8& lo){
  #pragma unroll
  for (int j = 0; j < 8; ++j){
    int k = kbase + j;
    float w = (k < K && n < Nout) ? W[(size_t)k * Nout + n] : 0.f;
    HL s = split1(w); hi[j] = s.hi; lo[j] = s.lo;
  }
}

// 3-product accurate bf16 MFMA: D += Ah*Bh + Al*Bh + Ah*Bl
__device__ __forceinline__ f32x4 mfma3(short8 ah, short8 al, short8 bh, short8 bl, f32x4 c){
  c = __builtin_amdgcn_mfma_f32_16x16x32_bf16(ah, bh, c, 0, 0, 0);
  c = __builtin_amdgcn_mfma_f32_16x16x32_bf16(al, bh, c, 0, 0, 0);
  c = __builtin_amdgcn_mfma_f32_16x16x32_bf16(ah, bl, c, 0, 0, 0);
  return c;
}

// pre-split stores: split once at producer, consumers ds_read_b128 hi/lo planes directly
__device__ __forceinline__ void sstore1(short* hp, short* lp, int idx, float x){
  HL s = split1(x); hp[idx] = s.hi; lp[idx] = s.lo;
}
__device__ __forceinline__ void sstore4(short* hp, short* lp, int idx, f32x4 v){
  short4v h, l;
  #pragma unroll
  for (int j = 0; j < 4; ++j){ HL s = split1(v[j]); h[j] = s.hi; l[j] = s.lo; }
  *(short4v*)(hp + idx) = h;
  *(short4v*)(lp + idx) = l;
}

// ---- edge kernel LDS geometry (all strides in shorts) ----
// H2 ALIASES the X region: X is dead after bar B (L1 its only reader), H2 is born
// after bar B (written by L2, read by L3, dead at bar D before the next stage).
// Row strides: gcd(stride_bytes,128)=16 -> 16 lanes land on 8 distinct 16B slots = 2-way (free).
#define XS   168            // X rows: 144 real cols + pad to K=160 (pads re-zeroed each stage)
#define H1S  72             // 64-col buffers
#define H2S  136            // 128-col buffer
#define OFF_XL   10752      // Xh @0 (64*168)
#define OFF_H2H  0          // aliases Xh
#define OFF_H2L  8704       // 64*136; [0,17408) fits inside X region [0,21504)
#define OFF_H1H  21504
#define OFF_H1L  26112      // 64*72=4608
#define OFF_DST  30720      // int dstI[2][64] parity
#define LDS_SHORTS 30976
#define LDS_BYTES  (LDS_SHORTS*2)   // 61952 B -> 2 blocks/CU (16 waves/CU)

// -------- edge kernel: 64 edges per block-tile, 8 waves, weights in regs, 4 barriers/tile ------
// MLP_msg 144->64->128->64->65; gate=sigmoid(col0); cols1..32 *g -> sum, 33..64 *g -> max
__global__ __launch_bounds__(512, 4) void edge_mfma(
    const float* __restrict__ nf, const float* __restrict__ ef,
    const int* __restrict__ src, const int* __restrict__ dst,
    const float* __restrict__ Wm1, const float* __restrict__ bm1,
    const float* __restrict__ Wm2, const float* __restrict__ bm2,
    const float* __restrict__ Wm3, const float* __restrict__ bm3,
    const float* __restrict__ Wm4, const float* __restrict__ bm4,
    float* __restrict__ nf1, float* __restrict__ nf2, int E)
{
  extern __shared__ short smem[];
  short* Xh  = smem;
  short* Xl  = smem + OFF_XL;
  short* H2h = smem + OFF_H2H;   // alias of X region
  short* H2l = smem + OFF_H2L;
  short* H1h = smem + OFF_H1H;
  short* H1l = smem + OFF_H1L;
  int*  dstI = (int*)(smem + OFF_DST);

  const int lane = threadIdx.x & 63, wv = threadIdx.x >> 6;
  const int nl = lane & 15, quad = lane >> 4;
  const int m1 = wv >> 2, nb1 = wv & 3;   // (m-half, n-block)
  const int slot = wv*4 + quad;           // 0..31, stages rows slot*2, slot*2+1

  // ---- loop-invariant B fragments (hi/lo bf16) in registers ----
  short8 B1h[5], B1l[5];
  #pragma unroll
  for (int kc = 0; kc < 5; ++kc) gatherB(Wm1, 144, 64,  kc*32 + quad*8, nb1*16 + nl, B1h[kc], B1l[kc]);
  short8 B2h[2][2], B2l[2][2];
  #pragma unroll
  for (int i = 0; i < 2; ++i)
    #pragma unroll
    for (int kc = 0; kc < 2; ++kc) gatherB(Wm2, 64, 128, kc*32 + quad*8, (nb1 + i*4)*16 + nl, B2h[i][kc], B2l[i][kc]);
  short8 B3h[4], B3l[4];
  #pragma unroll
  for (int kc = 0; kc < 4; ++kc) gatherB(Wm3, 128, 64,  kc*32 + quad*8, nb1*16 + nl, B3h[kc], B3l[kc]);
  short8 B4h[2], B4l[2];                  // tileA: cols nb1*16+nl
  #pragma unroll
  for (int kc = 0; kc < 2; ++kc) gatherB(Wm4, 64, 65, kc*32 + quad*8, nb1*16 + nl, B4h[kc], B4l[kc]);
  // gate fragment: lanes 0..7 broadcast col 0 (gate logit), lanes 8..15 broadcast col 64.
  const int gcol = (nl < 8) ? 0 : 64;
  short8 Bgh[2], Bgl[2];
  #pragma unroll
  for (int kc = 0; kc < 2; ++kc) gatherB(Wm4, 64, 65, kc*32 + quad*8, gcol, Bgh[kc], Bgl[kc]);

  const float bi1  = bm1[nb1*16 + nl];
  const float bi2a = bm2[nb1*16 + nl], bi2b = bm2[(nb1+4)*16 + nl];
  const float bi3  = bm3[nb1*16 + nl];
  const float bi4a = bm4[nb1*16 + nl];
  const float big  = bm4[gcol];
  // no init barrier needed: every LDS cell is written before it is read each tile
  // (X cols 0..143 + pads by stage, H1 by L1, H2 by L2, dstI by stage).

  const int ntiles = (E + 63) >> 6;
  int pp = 0;
  for (int t = blockIdx.x; t < ntiles; t += gridDim.x, pp ^= 1){
    // ---- stage X = [nf[src]|nf[dst]|ef|pad0], split once to hi/lo planes ----
    // Safe vs stragglers in L4(t-1): they read only H1 (all waves passed bar D) and
    // dstI (parity-buffered). X region reads (L3's H2) also done at bar D.
    #pragma unroll
    for (int r2 = 0; r2 < 2; ++r2){
      int row = slot*2 + r2;
      int e = (t << 6) + row;
      int ec = e < E ? e : 0;
      int s = src[ec], d = dst[ec];
      f32x4 v0 = *(const f32x4*)(nf + (size_t)s*64 + nl*4);
      f32x4 v1 = *(const f32x4*)(nf + (size_t)d*64 + nl*4);
      sstore4(Xh, Xl, row*XS + nl*4,      v0);
      sstore4(Xh, Xl, row*XS + 64 + nl*4, v1);
      if (nl < 4){
        f32x4 v2 = *(const f32x4*)(ef + (size_t)ec*16 + nl*4);
        sstore4(Xh, Xl, row*XS + 128 + nl*4, v2);
      } else if (nl < 8){
        // re-zero pad cols 144..159 (clobbered by aliased H2 last tile); 0*NaN = NaN in MFMA
        short4v z = {0,0,0,0};
        *(short4v*)(Xh + row*XS + 144 + (nl-4)*4) = z;
        *(short4v*)(Xl + row*XS + 144 + (nl-4)*4) = z;
      }
      if (nl == 5) dstI[pp*64 + row] = (e < E) ? d : -1;
    }
    __syncthreads();   // A: X visible; also drains this wave's prev-tile atomics

    // ---- L1: K=160 (144 real, pads zeroed), X -> H1 ----
    {
      f32x4 a1[2] = {{bi1,bi1,bi1,bi1},{bi1,bi1,bi1,bi1}};
      #pragma unroll
      for (int kc = 0; kc < 5; ++kc)
        #pragma unroll
        for (int mb = 0; mb < 2; ++mb){
          int ro = (m1*32 + mb*16 + nl)*XS + kc*32 + quad*8;
          short8 ah = *(const short8*)(Xh + ro);
          short8 al = *(const short8*)(Xl + ro);
          a1[mb] = mfma3(ah, al, B1h[kc], B1l[kc], a1[mb]);
        }
      #pragma unroll
      for (int mb = 0; mb < 2; ++mb)
        #pragma unroll
        for (int r = 0; r < 4; ++r)
          sstore1(H1h, H1l, (m1*32 + mb*16 + quad*4 + r)*H1S + nb1*16 + nl, lrelu(a1[mb][r]));
    }
    __syncthreads();   // B: all X reads done -> H2 may overwrite X region

    // ---- L2: K=64, dual n-block, H1 -> H2 (aliased over X) ----
    {
      f32x4 a2a[2] = {{bi2a,bi2a,bi2a,bi2a},{bi2a,bi2a,bi2a,bi2a}};
      f32x4 a2b[2] = {{bi2b,bi2b,bi2b,bi2b},{bi2b,bi2b,bi2b,bi2b}};
      #pragma unroll
      for (int kc = 0; kc < 2; ++kc)
        #pragma unroll
        for (int mb = 0; mb < 2; ++mb){
          int ro = (m1*32 + mb*16 + nl)*H1S + kc*32 + quad*8;
          short8 ah = *(const short8*)(H1h + ro);
          short8 al = *(const short8*)(H1l + ro);
          a2a[mb] = mfma3(ah, al, B2h[0][kc], B2l[0][kc], a2a[mb]);
          a2b[mb] = mfma3(ah, al, B2h[1][kc], B2l[1][kc], a2b[mb]);
        }
      #pragma unroll
      for (int mb = 0; mb < 2; ++mb)
        #pragma unroll
        for (int r = 0; r < 4; ++r){
          int row = m1*32 + mb*16 + quad*4 + r;
          sstore1(H2h, H2l, row*H2S + nb1*16 + nl,     lrelu(a2a[mb][r]));
          sstore1(H2h, H2l, row*H2S + (nb1+4)*16 + nl, lrelu(a2b[mb][r]));
        }
    }
    __syncthreads();   // C

    // ---- L3: K=128, H2 -> H1 (all L2 reads of H1 completed at C) ----
    {
      f32x4 a3[2] = {{bi3,bi3,bi3,bi3},{bi3,bi3,bi3,bi3}};
      #pragma unroll
      for (int kc = 0; kc < 4; ++kc)
        #pragma unroll
        for (int mb = 0; mb < 2; ++mb){
          int ro = (m1*32 + mb*16 + nl)*H2S + kc*32 + quad*8;
          short8 ah = *(const short8*)(H2h + ro);
          short8 al = *(const short8*)(H2l + ro);
          a3[mb] = mfma3(ah, al, B3h[kc], B3l[kc], a3[mb]);
        }
      #pragma unroll
      for (int mb = 0; mb < 2; ++mb)
        #pragma unroll
        for (int r = 0; r < 4; ++r)
          sstore1(H1h, H1l, (m1*32 + mb*16 + quad*4 + r)*H1S + nb1*16 + nl, lrelu(a3[mb][r]));
    }
    __syncthreads();   // D: H2 (X region) reads done -> next stage may overwrite

    // ---- L4: K=64, tileA + gate/col64 broadcast frags; scatter (fire-and-forget atomics) ----
    {
      f32x4 a4[2] = {{bi4a,bi4a,bi4a,bi4a},{bi4a,bi4a,bi4a,bi4a}};
      f32x4 ag[2] = {{big,big,big,big},{big,big,big,big}};
      #pragma unroll
      for (int kc = 0; kc < 2; ++kc)
        #pragma unroll
        for (int mb = 0; mb < 2; ++mb){
          int ro = (m1*32 + mb*16 + nl)*H1S + kc*32 + quad*8;
          short8 ah = *(const short8*)(H1h + ro);
          short8 al = *(const short8*)(H1l + ro);
          a4[mb] = mfma3(ah, al, B4h[kc], B4l[kc], a4[mb]);
          ag[mb] = mfma3(ah, al, Bgh[kc], Bgl[kc], ag[mb]);
        }
      const int n = nb1*16 + nl;
      #pragma unroll
      for (int mb = 0; mb < 2; ++mb)
        #pragma unroll
        for (int r = 0; r < 4; ++r){
          int row = m1*32 + mb*16 + quad*4 + r;
          float glog = __shfl(ag[mb][r], lane & 0x30);   // lane nl==0 of this quad holds col-0 logit
          float g = 1.f/(1.f + __expf(-glog));
          int d = dstI[pp*64 + row];
          if (d >= 0){
            float v = a4[mb][r] * g;
            if (n >= 1 && n <= 32)  atomicAdd(nf1 + (size_t)d*32 + (n-1), v);
            else if (n >= 33)       atomicMaxF(nf2 + (size_t)d*32 + (n-33), v);
            if (nb1 == 0 && nl == 8)                      // lanes 8..15 hold col-64 output
              atomicMaxF(nf2 + (size_t)d*32 + 31, ag[mb][r] * g);
          }
        }
    }
    // no tail barrier: next stage writes X region (dead since bar D) and dstI[pp^1]
  }
}

__device__ void zero_f(float* p, int n){
  for (int i = threadIdx.x; i < n; i += blockDim.x) p[i] = 0.f;
}

#define B1S 68    // h-buffer stride: 68%32=4 -> 2-way; 272B %16=0
#define C0S 132   // node buf0 stride: 132%32=4 -> 2-way; 528B %16=0

// RNE split A-chunk (8 f32 from LDS row) -> hi/lo bf16 fragments (node kernel path)
__device__ __forceinline__ void splitA(const float* arow, int k0, short8& hi, short8& lo){
  f32x4 x0 = *(const f32x4*)(arow + k0);
  f32x4 x1 = *(const f32x4*)(arow + k0 + 4);
  #pragma unroll
  for (int j = 0; j < 4; ++j){
    HL a = split1(x0[j]); hi[j]   = a.hi; lo[j]   = a.lo;
    HL b = split1(x1[j]); hi[4+j] = b.hi; lo[4+j] = b.lo;
  }
}

// -------- node kernel: 32 nodes per block-tile, 8 waves (unchanged; ~10% of runtime) --------
__global__ __launch_bounds__(512, 2) void node_mfma(
    const float* __restrict__ nf,
    const float* __restrict__ nf1, const float* __restrict__ nf2,
    const float* __restrict__ Wr1, const float* __restrict__ br1,
    const float* __restrict__ Wr2, const float* __restrict__ br2,
    const float* __restrict__ Wr3, const float* __restrict__ br3,
    const float* __restrict__ Wr4, const float* __restrict__ br4,
    float* __restrict__ out, int N)
{
  __shared__ float buf0[32*C0S];
  __shared__ float buf1[32*B1S];

  zero_f(buf0, 32*C0S);
  zero_f(buf1, 32*B1S);

  const int lane = threadIdx.x & 63, wv = threadIdx.x >> 6;
  const int nl = lane & 15, quad = lane >> 4;
  const int m = wv >> 2, nb = wv & 3;

  short8 B1h[4], B1l[4];
  #pragma unroll
  for (int kc = 0; kc < 4; ++kc) gatherB(Wr1, 128, 64,  kc*32 + quad*8, nb*16 + nl, B1h[kc], B1l[kc]);
  short8 B2h[2][2], B2l[2][2];
  #pragma unroll
  for (int i = 0; i < 2; ++i)
    #pragma unroll
    for (int kc = 0; kc < 2; ++kc) gatherB(Wr2, 64, 128, kc*32 + quad*8, (nb + i*4)*16 + nl, B2h[i][kc], B2l[i][kc]);
  short8 B3h[4], B3l[4];
  #pragma unroll
  for (int kc = 0; kc < 4; ++kc) gatherB(Wr3, 128, 64,  kc*32 + quad*8, nb*16 + nl, B3h[kc], B3l[kc]);
  short8 B4h[2], B4l[2];
  #pragma unroll
  for (int kc = 0; kc < 2; ++kc) gatherB(Wr4, 64, 64,   kc*32 + quad*8, nb*16 + nl, B4h[kc], B4l[kc]);

  const float bi1  = br1[nb*16 + nl];
  const float bi2a = br2[nb*16 + nl], bi2b = br2[(nb+4)*16 + nl];
  const float bi3  = br3[nb*16 + nl];
  const float bi4  = br4[nb*16 + nl];
  __syncthreads();

  const int ntiles = (N + 31) >> 5;
  for (int t = blockIdx.x; t < ntiles; t += gridDim.x){
    const int base = t << 5;
    {
      int row = wv*4 + quad;
      int n = base + row;
      int nc = n < N ? n : 0;
      *(f32x4*)(buf0 + row*C0S + nl*4) = *(const f32x4*)(nf + (size_t)nc*64 + nl*4);
      if (nl < 8){
        *(f32x4*)(buf0 + row*C0S + 64 + nl*4) = *(const f32x4*)(nf1 + (size_t)nc*32 + nl*4);
      } else {
        f32x4 v = *(const f32x4*)(nf2 + (size_t)nc*32 + (nl-8)*4);
        #pragma unroll
        for (int j = 0; j < 4; ++j) if (!(v[j] >= -3.0e38f)) v[j] = 0.f;  // -inf/NaN -> 0
        *(f32x4*)(buf0 + row*C0S + 96 + (nl-8)*4) = v;
      }
    }
    __syncthreads();

    f32x4 a1 = {bi1, bi1, bi1, bi1};
    {
      const float* arow = buf0 + (m*16 + nl)*C0S;
      #pragma unroll
      for (int kc = 0; kc < 4; ++kc){
        short8 ah, al; splitA(arow, kc*32 + quad*8, ah, al);
        a1 = mfma3(ah, al, B1h[kc], B1l[kc], a1);
      }
    }
    #pragma unroll
    for (int r = 0; r < 4; ++r)
      buf1[(m*16 + quad*4 + r)*B1S + nb*16 + nl] = lrelu(a1[r]);
    __syncthreads();

    f32x4 a2a = {bi2a, bi2a, bi2a, bi2a}, a2b = {bi2b, bi2b, bi2b, bi2b};
    {
      const float* arow = buf1 + (m*16 + nl)*B1S;
      #pragma unroll
      for (int kc = 0; kc < 2; ++kc){
        short8 ah, al; splitA(arow, kc*32 + quad*8, ah, al);
        a2a = mfma3(ah, al, B2h[0][kc], B2l[0][kc], a2a);
        a2b = mfma3(ah, al, B2h[1][kc], B2l[1][kc], a2b);
      }
    }
    #pragma unroll
    for (int r = 0; r < 4; ++r){
      buf0[(m*16 + quad*4 + r)*C0S + nb*16 + nl]     = lrelu(a2a[r]);
      buf0[(m*16 + quad*4 + r)*C0S + (nb+4)*16 + nl] = lrelu(a2b[r]);
    }
    __syncthreads();

    f32x4 a3 = {bi3, bi3, bi3, bi3};
    {
      const float* arow = buf0 + (m*16 + nl)*C0S;
      #pragma unroll
      for (int kc = 0; kc < 4; ++kc){
        short8 ah, al; splitA(arow, kc*32 + quad*8, ah, al);
        a3 = mfma3(ah, al, B3h[kc], B3l[kc], a3);
      }
    }
    #pragma unroll
    for (int r = 0; r < 4; ++r)
      buf1[(m*16 + quad*4 + r)*B1S + nb*16 + nl] = lrelu(a3[r]);
    __syncthreads();

    f32x4 a4 = {bi4, bi4, bi4, bi4};
    {
      const float* arow = buf1 + (m*16 + nl)*B1S;
      #pragma unroll
      for (int kc = 0; kc < 2; ++kc){
        short8 ah, al; splitA(arow, kc*32 + quad*8, ah, al);
        a4 = mfma3(ah, al, B4h[kc], B4l[kc], a4);
      }
    }
    #pragma unroll
    for (int r = 0; r < 4; ++r){
      int n = base + m*16 + quad*4 + r;
      if (n < N) out[(size_t)n*64 + nb*16 + nl] = a4[r];
    }
  }
}

extern "C" void kernel_launch(void* const* d_in, const int* in_sizes, int n_in,
                              void* d_out, int out_size, void* d_ws, size_t ws_size,
                              hipStream_t stream) {
  const float* nf  = (const float*)d_in[0];
  const float* ef  = (const float*)d_in[1];
  const int*   src = (const int*)d_in[2];
  const int*   dst = (const int*)d_in[3];

  const int N = in_sizes[0] / 64;
  const int E = in_sizes[2];

  float* nf1 = (float*)d_ws;               // [N,32] segment-sum
  float* nf2 = nf1 + (size_t)N * 32;       // [N,32] segment-max

  static bool attr_set = false;
  if (!attr_set){
    hipFuncSetAttribute((const void*)edge_mfma,
                        hipFuncAttributeMaxDynamicSharedMemorySize, LDS_BYTES);
    attr_set = true;
  }

  init_ws<<<2048, 256, 0, stream>>>(nf1, nf2, N * 32);

  edge_mfma<<<512, 512, LDS_BYTES, stream>>>(
      nf, ef, src, dst,
      (const float*)d_in[4],  (const float*)d_in[5],  (const float*)d_in[6],  (const float*)d_in[7],
      (const float*)d_in[8],  (const float*)d_in[9],  (const float*)d_in[10], (const float*)d_in[11],
      nf1, nf2, E);

  node_mfma<<<512, 512, 0, stream>>>(
      nf, nf1, nf2,
      (const float*)d_in[12], (const float*)d_in[13], (const float*)d_in[14], (const float*)d_in[15],
      (const float*)d_in[16], (const float*)d_in[17], (const float*)d_in[18], (const float*)d_in[19],
      (float*)d_out, N);
}

// Round 4
// 1422.159 us; speedup vs baseline: 1.0452x; 1.0452x over previous
//
#include <hip/hip_runtime.h>

typedef unsigned int u32;
typedef __attribute__((ext_vector_type(8))) short short8;
typedef __attribute__((ext_vector_type(4))) short short4v;
typedef __attribute__((ext_vector_type(4))) float f32x4;

__device__ __forceinline__ float lrelu(float x){ return x > 0.f ? x : 0.2f*x; }

// float atomic max via sign-split (dest init -inf)
__device__ __forceinline__ void atomicMaxF(float* a, float v){
  if (__float_as_int(v) >= 0) atomicMax((int*)a, __float_as_int(v));
  else                        atomicMin((u32*)a, __float_as_uint(v));
}

__global__ void init_ws(float* __restrict__ nf1, float* __restrict__ nf2, int n32,
                        int* __restrict__ cnt, int ncnt){
  int i = blockIdx.x*blockDim.x + threadIdx.x;
  int st = gridDim.x*blockDim.x;
  for (int j = i; j < n32; j += st){ nf1[j] = 0.f; nf2[j] = -__builtin_inff(); }
  if (cnt){ for (int j = i; j < ncnt; j += st) cnt[j] = 0; }
}

// ---- counting-sort pre-pass: group edges by dst so the scatter can run-merge ----
__global__ void hist_dst(const int* __restrict__ dst, int* __restrict__ cnt, int E){
  int e = blockIdx.x*blockDim.x + threadIdx.x;
  int st = gridDim.x*blockDim.x;
  for (; e < E; e += st) atomicAdd(&cnt[dst[e]], 1);
}

// single-block exclusive scan of cnt[0..N) -> cursor (few µs at N=50k)
__global__ void scan_cursor(const int* __restrict__ cnt, int* __restrict__ cursor, int N){
  __shared__ int sh[1024];
  __shared__ int carry;
  if (threadIdx.x == 0) carry = 0;
  __syncthreads();
  for (int base = 0; base < N; base += 1024){
    int i = base + threadIdx.x;
    int v = (i < N) ? cnt[i] : 0;
    sh[threadIdx.x] = v;
    __syncthreads();
    for (int off = 1; off < 1024; off <<= 1){
      int t = (threadIdx.x >= off) ? sh[threadIdx.x - off] : 0;
      __syncthreads();
      sh[threadIdx.x] += t;
      __syncthreads();
    }
    if (i < N) cursor[i] = carry + sh[threadIdx.x] - v;   // exclusive prefix
    int total = sh[1023];
    __syncthreads();
    if (threadIdx.x == 0) carry += total;
    __syncthreads();
  }
}

__global__ void permute_edges(const int* __restrict__ dst, int* __restrict__ cursor,
                              int* __restrict__ perm, int E){
  int e = blockIdx.x*blockDim.x + threadIdx.x;
  int st = gridDim.x*blockDim.x;
  for (; e < E; e += st){
    int p = atomicAdd(&cursor[dst[e]], 1);
    perm[p] = e;                       // within-dst order is racy: sum-order change only
  }
}

// RNE split: x = bf16(hi) + bf16(lo) + O(2^-18 x).
struct HL { short hi, lo; };
__device__ __forceinline__ HL split1(float x){
  u32 u = __float_as_uint(x);
  u32 r = u + 0x7FFFu + ((u >> 16) & 1u);
  float l = x - __uint_as_float(r & 0xFFFF0000u);
  HL o; o.hi = (short)(r >> 16); o.lo = (short)(__float_as_uint(l) >> 16);
  return o;
}

// one-time gather of a B fragment (W row-major [K][Nout], f32) with zero-fill OOB
__device__ __forceinline__ void gatherB(const float* __restrict__ W, int K, int Nout,
                                        int kbase, int n, short8& hi, short8& lo){
  #pragma unroll
  for (int j = 0; j < 8; ++j){
    int k = kbase + j;
    float w = (k < K && n < Nout) ? W[(size_t)k * Nout + n] : 0.f;
    HL s = split1(w); hi[j] = s.hi; lo[j] = s.lo;
  }
}

// 3-product accurate bf16 MFMA: D += Ah*Bh + Al*Bh + Ah*Bl
__device__ __forceinline__ f32x4 mfma3(short8 ah, short8 al, short8 bh, short8 bl, f32x4 c){
  c = __builtin_amdgcn_mfma_f32_16x16x32_bf16(ah, bh, c, 0, 0, 0);
  c = __builtin_amdgcn_mfma_f32_16x16x32_bf16(al, bh, c, 0, 0, 0);
  c = __builtin_amdgcn_mfma_f32_16x16x32_bf16(ah, bl, c, 0, 0, 0);
  return c;
}

// pre-split stores: split once at producer, consumers ds_read_b128 hi/lo planes directly
__device__ __forceinline__ void sstore1(short* hp, short* lp, int idx, float x){
  HL s = split1(x); hp[idx] = s.hi; lp[idx] = s.lo;
}
__device__ __forceinline__ void sstore4(short* hp, short* lp, int idx, f32x4 v){
  short4v h, l;
  #pragma unroll
  for (int j = 0; j < 4; ++j){ HL s = split1(v[j]); h[j] = s.hi; l[j] = s.lo; }
  *(short4v*)(hp + idx) = h;
  *(short4v*)(lp + idx) = l;
}

// ---- edge kernel LDS geometry (all strides in shorts) ----
// H2 ALIASES the X region: X dead after bar B (L1 its only reader); H2 born after bar B,
// dead at bar D before the next stage.
#define XS   168            // X rows: 144 real cols + pad to K=160 (pads re-zeroed each stage)
#define H1S  72             // 64-col buffers
#define H2S  136            // 128-col buffer
#define OFF_XL   10752      // Xh @0 (64*168)
#define OFF_H2H  0          // aliases Xh
#define OFF_H2L  8704       // 64*136; [0,17408) inside X region [0,21504)
#define OFF_H1H  21504
#define OFF_H1L  26112      // 64*72=4608
#define OFF_DST  30720      // int dstI[2][64] parity
#define LDS_SHORTS 30976
#define LDS_BYTES  (LDS_SHORTS*2)   // 61952 B

// -------- edge kernel: 64 edges/block-tile, 8 waves, weights in regs, 4 barriers/tile --------
// MLP_msg 144->64->128->64->65; gate=sigmoid(col0); cols1..32 *g -> sum, 33..64 *g -> max.
// Edges arrive dst-sorted (perm) -> per-lane run-merge before atomics.
// NOTE: ~192 regs/wave needed -> hard cap 8 waves/CU; do NOT tighten launch_bounds
// (rounds 1&3: forcing more waves spills -> FETCH explodes).
__global__ __launch_bounds__(512, 2) void edge_mfma(
    const float* __restrict__ nf, const float* __restrict__ ef,
    const int* __restrict__ src, const int* __restrict__ dst,
    const int* __restrict__ perm,
    const float* __restrict__ Wm1, const float* __restrict__ bm1,
    const float* __restrict__ Wm2, const float* __restrict__ bm2,
    const float* __restrict__ Wm3, const float* __restrict__ bm3,
    const float* __restrict__ Wm4, const float* __restrict__ bm4,
    float* __restrict__ nf1, float* __restrict__ nf2, int E)
{
  extern __shared__ short smem[];
  short* Xh  = smem;
  short* Xl  = smem + OFF_XL;
  short* H2h = smem + OFF_H2H;   // alias of X region
  short* H2l = smem + OFF_H2L;
  short* H1h = smem + OFF_H1H;
  short* H1l = smem + OFF_H1L;
  int*  dstI = (int*)(smem + OFF_DST);

  const int lane = threadIdx.x & 63, wv = threadIdx.x >> 6;
  const int nl = lane & 15, quad = lane >> 4;
  const int m1 = wv >> 2, nb1 = wv & 3;   // (m-half, n-block)
  const int slot = wv*4 + quad;           // 0..31, stages rows slot*2, slot*2+1

  // ---- loop-invariant B fragments (hi/lo bf16) in registers ----
  short8 B1h[5], B1l[5];
  #pragma unroll
  for (int kc = 0; kc < 5; ++kc) gatherB(Wm1, 144, 64,  kc*32 + quad*8, nb1*16 + nl, B1h[kc], B1l[kc]);
  short8 B2h[2][2], B2l[2][2];
  #pragma unroll
  for (int i = 0; i < 2; ++i)
    #pragma unroll
    for (int kc = 0; kc < 2; ++kc) gatherB(Wm2, 64, 128, kc*32 + quad*8, (nb1 + i*4)*16 + nl, B2h[i][kc], B2l[i][kc]);
  short8 B3h[4], B3l[4];
  #pragma unroll
  for (int kc = 0; kc < 4; ++kc) gatherB(Wm3, 128, 64,  kc*32 + quad*8, nb1*16 + nl, B3h[kc], B3l[kc]);
  short8 B4h[2], B4l[2];                  // tileA: cols nb1*16+nl
  #pragma unroll
  for (int kc = 0; kc < 2; ++kc) gatherB(Wm4, 64, 65, kc*32 + quad*8, nb1*16 + nl, B4h[kc], B4l[kc]);
  // gate fragment: lanes 0..7 broadcast col 0 (gate logit), lanes 8..15 broadcast col 64.
  const int gcol = (nl < 8) ? 0 : 64;
  short8 Bgh[2], Bgl[2];
  #pragma unroll
  for (int kc = 0; kc < 2; ++kc) gatherB(Wm4, 64, 65, kc*32 + quad*8, gcol, Bgh[kc], Bgl[kc]);

  const float bi1  = bm1[nb1*16 + nl];
  const float bi2a = bm2[nb1*16 + nl], bi2b = bm2[(nb1+4)*16 + nl];
  const float bi3  = bm3[nb1*16 + nl];
  const float bi4a = bm4[nb1*16 + nl];
  const float big  = bm4[gcol];

  const int ntiles = (E + 63) >> 6;
  int pp = 0;
  for (int t = blockIdx.x; t < ntiles; t += gridDim.x, pp ^= 1){
    // ---- stage X = [nf[src]|nf[dst]|ef|pad0], split once to hi/lo planes ----
    #pragma unroll
    for (int r2 = 0; r2 < 2; ++r2){
      int row = slot*2 + r2;
      int e = (t << 6) + row;
      int ec = e < E ? e : 0;
      int eid = perm ? perm[ec] : ec;
      int s = src[eid], d = dst[eid];
      f32x4 v0 = *(const f32x4*)(nf + (size_t)s*64 + nl*4);
      f32x4 v1 = *(const f32x4*)(nf + (size_t)d*64 + nl*4);
      sstore4(Xh, Xl, row*XS + nl*4,      v0);
      sstore4(Xh, Xl, row*XS + 64 + nl*4, v1);
      if (nl < 4){
        f32x4 v2 = *(const f32x4*)(ef + (size_t)eid*16 + nl*4);
        sstore4(Xh, Xl, row*XS + 128 + nl*4, v2);
      } else if (nl < 8){
        // re-zero pad cols 144..159 (clobbered by aliased H2 last tile); 0*NaN = NaN in MFMA
        short4v z = {0,0,0,0};
        *(short4v*)(Xh + row*XS + 144 + (nl-4)*4) = z;
        *(short4v*)(Xl + row*XS + 144 + (nl-4)*4) = z;
      }
      if (nl == 5) dstI[pp*64 + row] = (e < E) ? d : -1;
    }
    __syncthreads();   // A: X visible; also drains this wave's prev-tile atomics

    // ---- L1: K=160 (144 real, pads zeroed), X -> H1 ----
    {
      f32x4 a1[2] = {{bi1,bi1,bi1,bi1},{bi1,bi1,bi1,bi1}};
      #pragma unroll
      for (int kc = 0; kc < 5; ++kc)
        #pragma unroll
        for (int mb = 0; mb < 2; ++mb){
          int ro = (m1*32 + mb*16 + nl)*XS + kc*32 + quad*8;
          short8 ah = *(const short8*)(Xh + ro);
          short8 al = *(const short8*)(Xl + ro);
          a1[mb] = mfma3(ah, al, B1h[kc], B1l[kc], a1[mb]);
        }
      #pragma unroll
      for (int mb = 0; mb < 2; ++mb)
        #pragma unroll
        for (int r = 0; r < 4; ++r)
          sstore1(H1h, H1l, (m1*32 + mb*16 + quad*4 + r)*H1S + nb1*16 + nl, lrelu(a1[mb][r]));
    }
    __syncthreads();   // B: all X reads done -> H2 may overwrite X region

    // ---- L2: K=64, dual n-block, H1 -> H2 (aliased over X) ----
    {
      f32x4 a2a[2] = {{bi2a,bi2a,bi2a,bi2a},{bi2a,bi2a,bi2a,bi2a}};
      f32x4 a2b[2] = {{bi2b,bi2b,bi2b,bi2b},{bi2b,bi2b,bi2b,bi2b}};
      #pragma unroll
      for (int kc = 0; kc < 2; ++kc)
        #pragma unroll
        for (int mb = 0; mb < 2; ++mb){
          int ro = (m1*32 + mb*16 + nl)*H1S + kc*32 + quad*8;
          short8 ah = *(const short8*)(H1h + ro);
          short8 al = *(const short8*)(H1l + ro);
          a2a[mb] = mfma3(ah, al, B2h[0][kc], B2l[0][kc], a2a[mb]);
          a2b[mb] = mfma3(ah, al, B2h[1][kc], B2l[1][kc], a2b[mb]);
        }
      #pragma unroll
      for (int mb = 0; mb < 2; ++mb)
        #pragma unroll
        for (int r = 0; r < 4; ++r){
          int row = m1*32 + mb*16 + quad*4 + r;
          sstore1(H2h, H2l, row*H2S + nb1*16 + nl,     lrelu(a2a[mb][r]));
          sstore1(H2h, H2l, row*H2S + (nb1+4)*16 + nl, lrelu(a2b[mb][r]));
        }
    }
    __syncthreads();   // C

    // ---- L3: K=128, H2 -> H1 (all L2 reads of H1 completed at C) ----
    {
      f32x4 a3[2] = {{bi3,bi3,bi3,bi3},{bi3,bi3,bi3,bi3}};
      #pragma unroll
      for (int kc = 0; kc < 4; ++kc)
        #pragma unroll
        for (int mb = 0; mb < 2; ++mb){
          int ro = (m1*32 + mb*16 + nl)*H2S + kc*32 + quad*8;
          short8 ah = *(const short8*)(H2h + ro);
          short8 al = *(const short8*)(H2l + ro);
          a3[mb] = mfma3(ah, al, B3h[kc], B3l[kc], a3[mb]);
        }
      #pragma unroll
      for (int mb = 0; mb < 2; ++mb)
        #pragma unroll
        for (int r = 0; r < 4; ++r)
          sstore1(H1h, H1l, (m1*32 + mb*16 + quad*4 + r)*H1S + nb1*16 + nl, lrelu(a3[mb][r]));
    }
    __syncthreads();   // D: H2 (X region) reads done -> next stage may overwrite

    // ---- L4: K=64, tileA + gate/col64 broadcast frags; run-merged scatter ----
    {
      f32x4 a4[2] = {{bi4a,bi4a,bi4a,bi4a},{bi4a,bi4a,bi4a,bi4a}};
      f32x4 ag[2] = {{big,big,big,big},{big,big,big,big}};
      #pragma unroll
      for (int kc = 0; kc < 2; ++kc)
        #pragma unroll
        for (int mb = 0; mb < 2; ++mb){
          int ro = (m1*32 + mb*16 + nl)*H1S + kc*32 + quad*8;
          short8 ah = *(const short8*)(H1h + ro);
          short8 al = *(const short8*)(H1l + ro);
          a4[mb] = mfma3(ah, al, B4h[kc], B4l[kc], a4[mb]);
          ag[mb] = mfma3(ah, al, Bgh[kc], Bgl[kc], ag[mb]);
        }

      // This lane's 8 rows, in row order: s=0..7 -> row m1*32 + (s>>2)*16 + quad*4 + (s&3).
      // dst-sorted => dst non-decreasing over rows => equal dst are ADJACENT in this seq.
      const int n = nb1*16 + nl;
      float vals[8], mv[8]; int ds8[8];
      #pragma unroll
      for (int s = 0; s < 8; ++s){
        int mb = s >> 2, r = s & 3;
        int row = m1*32 + mb*16 + quad*4 + r;
        float glog = __shfl(ag[mb][r], lane & 0x30);   // quad's nl==0 lane holds col-0 logit
        float g = 1.f/(1.f + __expf(-glog));
        ds8[s]  = dstI[pp*64 + row];
        vals[s] = a4[mb][r] * g;
        mv[s]   = ag[mb][r] * g;                       // col-64 gated value on nl==8 lanes
      }
      if (n >= 1 && n <= 32){
        int dc = ds8[0]; float acc = vals[0];
        #pragma unroll
        for (int s = 1; s < 8; ++s){
          if (ds8[s] == dc) acc += vals[s];
          else { if (dc >= 0) atomicAdd(nf1 + (size_t)dc*32 + (n-1), acc); dc = ds8[s]; acc = vals[s]; }
        }
        if (dc >= 0) atomicAdd(nf1 + (size_t)dc*32 + (n-1), acc);
      } else if (n >= 33){
        int dc = ds8[0]; float acc = vals[0];
        #pragma unroll
        for (int s = 1; s < 8; ++s){
          if (ds8[s] == dc) acc = fmaxf(acc, vals[s]);
          else { if (dc >= 0) atomicMaxF(nf2 + (size_t)dc*32 + (n-33), acc); dc = ds8[s]; acc = vals[s]; }
        }
        if (dc >= 0) atomicMaxF(nf2 + (size_t)dc*32 + (n-33), acc);
      }
      if (nb1 == 0 && nl == 8){                        // col 64 -> nf2 col 31
        int dc = ds8[0]; float acc = mv[0];
        #pragma unroll
        for (int s = 1; s < 8; ++s){
          if (ds8[s] == dc) acc = fmaxf(acc, mv[s]);
          else { if (dc >= 0) atomicMaxF(nf2 + (size_t)dc*32 + 31, acc); dc = ds8[s]; acc = mv[s]; }
        }
        if (dc >= 0) atomicMaxF(nf2 + (size_t)dc*32 + 31, acc);
      }
    }
    // no tail barrier: next stage writes X region (dead since bar D) and dstI[pp^1]
  }
}

__device__ void zero_f(float* p, int n){
  for (int i = threadIdx.x; i < n; i += blockDim.x) p[i] = 0.f;
}

#define B1S 68    // h-buffer stride
#define C0S 132   // node buf0 stride

// RNE split A-chunk (8 f32 from LDS row) -> hi/lo bf16 fragments (node kernel path)
__device__ __forceinline__ void splitA(const float* arow, int k0, short8& hi, short8& lo){
  f32x4 x0 = *(const f32x4*)(arow + k0);
  f32x4 x1 = *(const f32x4*)(arow + k0 + 4);
  #pragma unroll
  for (int j = 0; j < 4; ++j){
    HL a = split1(x0[j]); hi[j]   = a.hi; lo[j]   = a.lo;
    HL b = split1(x1[j]); hi[4+j] = b.hi; lo[4+j] = b.lo;
  }
}

// -------- node kernel: 32 nodes per block-tile, 8 waves (unchanged) --------
__global__ __launch_bounds__(512, 2) void node_mfma(
    const float* __restrict__ nf,
    const float* __restrict__ nf1, const float* __restrict__ nf2,
    const float* __restrict__ Wr1, const float* __restrict__ br1,
    const float* __restrict__ Wr2, const float* __restrict__ br2,
    const float* __restrict__ Wr3, const float* __restrict__ br3,
    const float* __restrict__ Wr4, const float* __restrict__ br4,
    float* __restrict__ out, int N)
{
  __shared__ float buf0[32*C0S];
  __shared__ float buf1[32*B1S];

  zero_f(buf0, 32*C0S);
  zero_f(buf1, 32*B1S);

  const int lane = threadIdx.x & 63, wv = threadIdx.x >> 6;
  const int nl = lane & 15, quad = lane >> 4;
  const int m = wv >> 2, nb = wv & 3;

  short8 B1h[4], B1l[4];
  #pragma unroll
  for (int kc = 0; kc < 4; ++kc) gatherB(Wr1, 128, 64,  kc*32 + quad*8, nb*16 + nl, B1h[kc], B1l[kc]);
  short8 B2h[2][2], B2l[2][2];
  #pragma unroll
  for (int i = 0; i < 2; ++i)
    #pragma unroll
    for (int kc = 0; kc < 2; ++kc) gatherB(Wr2, 64, 128, kc*32 + quad*8, (nb + i*4)*16 + nl, B2h[i][kc], B2l[i][kc]);
  short8 B3h[4], B3l[4];
  #pragma unroll
  for (int kc = 0; kc < 4; ++kc) gatherB(Wr3, 128, 64,  kc*32 + quad*8, nb*16 + nl, B3h[kc], B3l[kc]);
  short8 B4h[2], B4l[2];
  #pragma unroll
  for (int kc = 0; kc < 2; ++kc) gatherB(Wr4, 64, 64,   kc*32 + quad*8, nb*16 + nl, B4h[kc], B4l[kc]);

  const float bi1  = br1[nb*16 + nl];
  const float bi2a = br2[nb*16 + nl], bi2b = br2[(nb+4)*16 + nl];
  const float bi3  = br3[nb*16 + nl];
  const float bi4  = br4[nb*16 + nl];
  __syncthreads();

  const int ntiles = (N + 31) >> 5;
  for (int t = blockIdx.x; t < ntiles; t += gridDim.x){
    const int base = t << 5;
    {
      int row = wv*4 + quad;
      int n = base + row;
      int nc = n < N ? n : 0;
      *(f32x4*)(buf0 + row*C0S + nl*4) = *(const f32x4*)(nf + (size_t)nc*64 + nl*4);
      if (nl < 8){
        *(f32x4*)(buf0 + row*C0S + 64 + nl*4) = *(const f32x4*)(nf1 + (size_t)nc*32 + nl*4);
      } else {
        f32x4 v = *(const f32x4*)(nf2 + (size_t)nc*32 + (nl-8)*4);
        #pragma unroll
        for (int j = 0; j < 4; ++j) if (!(v[j] >= -3.0e38f)) v[j] = 0.f;  // -inf/NaN -> 0
        *(f32x4*)(buf0 + row*C0S + 96 + (nl-8)*4) = v;
      }
    }
    __syncthreads();

    f32x4 a1 = {bi1, bi1, bi1, bi1};
    {
      const float* arow = buf0 + (m*16 + nl)*C0S;
      #pragma unroll
      for (int kc = 0; kc < 4; ++kc){
        short8 ah, al; splitA(arow, kc*32 + quad*8, ah, al);
        a1 = mfma3(ah, al, B1h[kc], B1l[kc], a1);
      }
    }
    #pragma unroll
    for (int r = 0; r < 4; ++r)
      buf1[(m*16 + quad*4 + r)*B1S + nb*16 + nl] = lrelu(a1[r]);
    __syncthreads();

    f32x4 a2a = {bi2a, bi2a, bi2a, bi2a}, a2b = {bi2b, bi2b, bi2b, bi2b};
    {
      const float* arow = buf1 + (m*16 + nl)*B1S;
      #pragma unroll
      for (int kc = 0; kc < 2; ++kc){
        short8 ah, al; splitA(arow, kc*32 + quad*8, ah, al);
        a2a = mfma3(ah, al, B2h[0][kc], B2l[0][kc], a2a);
        a2b = mfma3(ah, al, B2h[1][kc], B2l[1][kc], a2b);
      }
    }
    #pragma unroll
    for (int r = 0; r < 4; ++r){
      buf0[(m*16 + quad*4 + r)*C0S + nb*16 + nl]     = lrelu(a2a[r]);
      buf0[(m*16 + quad*4 + r)*C0S + (nb+4)*16 + nl] = lrelu(a2b[r]);
    }
    __syncthreads();

    f32x4 a3 = {bi3, bi3, bi3, bi3};
    {
      const float* arow = buf0 + (m*16 + nl)*C0S;
      #pragma unroll
      for (int kc = 0; kc < 4; ++kc){
        short8 ah, al; splitA(arow, kc*32 + quad*8, ah, al);
        a3 = mfma3(ah, al, B3h[kc], B3l[kc], a3);
      }
    }
    #pragma unroll
    for (int r = 0; r < 4; ++r)
      buf1[(m*16 + quad*4 + r)*B1S + nb*16 + nl] = lrelu(a3[r]);
    __syncthreads();

    f32x4 a4 = {bi4, bi4, bi4, bi4};
    {
      const float* arow = buf1 + (m*16 + nl)*B1S;
      #pragma unroll
      for (int kc = 0; kc < 2; ++kc){
        short8 ah, al; splitA(arow, kc*32 + quad*8, ah, al);
        a4 = mfma3(ah, al, B4h[kc], B4l[kc], a4);
      }
    }
    #pragma unroll
    for (int r = 0; r < 4; ++r){
      int n = base + m*16 + quad*4 + r;
      if (n < N) out[(size_t)n*64 + nb*16 + nl] = a4[r];
    }
  }
}

extern "C" void kernel_launch(void* const* d_in, const int* in_sizes, int n_in,
                              void* d_out, int out_size, void* d_ws, size_t ws_size,
                              hipStream_t stream) {
  const float* nf  = (const float*)d_in[0];
  const float* ef  = (const float*)d_in[1];
  const int*   src = (const int*)d_in[2];
  const int*   dst = (const int*)d_in[3];

  const int N = in_sizes[0] / 64;
  const int E = in_sizes[2];

  float* nf1 = (float*)d_ws;               // [N,32] segment-sum
  float* nf2 = nf1 + (size_t)N * 32;       // [N,32] segment-max

  // optional sort workspace after nf1/nf2
  size_t base_b  = (size_t)N * 64 * 4;
  size_t extra_b = (size_t)N * 4 /*cnt*/ + (size_t)N * 4 /*cursor*/ + (size_t)E * 4 /*perm*/;
  bool sorted = (ws_size >= base_b + extra_b);
  int* cnt    = (int*)((char*)d_ws + base_b);
  int* cursor = cnt + N;
  int* perm   = cursor + N;

  static bool attr_set = false;
  if (!attr_set){
    hipFuncSetAttribute((const void*)edge_mfma,
                        hipFuncAttributeMaxDynamicSharedMemorySize, LDS_BYTES);
    attr_set = true;
  }

  init_ws<<<2048, 256, 0, stream>>>(nf1, nf2, N * 32, sorted ? cnt : nullptr, N);

  if (sorted){
    hist_dst<<<1024, 256, 0, stream>>>(dst, cnt, E);
    scan_cursor<<<1, 1024, 0, stream>>>(cnt, cursor, N);
    permute_edges<<<1024, 256, 0, stream>>>(dst, cursor, perm, E);
  }

  edge_mfma<<<512, 512, LDS_BYTES, stream>>>(
      nf, ef, src, dst, sorted ? perm : nullptr,
      (const float*)d_in[4],  (const float*)d_in[5],  (const float*)d_in[6],  (const float*)d_in[7],
      (const float*)d_in[8],  (const float*)d_in[9],  (const float*)d_in[10], (const float*)d_in[11],
      nf1, nf2, E);

  node_mfma<<<512, 512, 0, stream>>>(
      nf, nf1, nf2,
      (const float*)d_in[12], (const float*)d_in[13], (const float*)d_in[14], (const float*)d_in[15],
      (const float*)d_in[16], (const float*)d_in[17], (const float*)d_in[18], (const float*)d_in[19],
      (float*)d_out, N);
}

// Round 5
// 1130.326 us; speedup vs baseline: 1.3150x; 1.2582x over previous
//
#include <hip/hip_runtime.h>

typedef unsigned int u32;
typedef __attribute__((ext_vector_type(8))) short short8;
typedef __attribute__((ext_vector_type(4))) short short4v;
typedef __attribute__((ext_vector_type(4))) float f32x4;

__device__ __forceinline__ float lrelu(float x){ return x > 0.f ? x : 0.2f*x; }

// float atomic max via sign-split (dest init -inf)
__device__ __forceinline__ void atomicMaxF(float* a, float v){
  if (__float_as_int(v) >= 0) atomicMax((int*)a, __float_as_int(v));
  else                        atomicMin((u32*)a, __float_as_uint(v));
}

__global__ void init_ws(float* __restrict__ nf1, float* __restrict__ nf2, int n32){
  int i = blockIdx.x*blockDim.x + threadIdx.x;
  int st = gridDim.x*blockDim.x;
  for (; i < n32; i += st){ nf1[i] = 0.f; nf2[i] = -__builtin_inff(); }
}

// RNE split: x = bf16(hi) + bf16(lo) + O(2^-18 x).
struct HL { short hi, lo; };
__device__ __forceinline__ HL split1(float x){
  u32 u = __float_as_uint(x);
  u32 r = u + 0x7FFFu + ((u >> 16) & 1u);
  float l = x - __uint_as_float(r & 0xFFFF0000u);
  HL o; o.hi = (short)(r >> 16); o.lo = (short)(__float_as_uint(l) >> 16);
  return o;
}

// one-time gather of a B fragment (W row-major [K][Nout], f32) with zero-fill OOB
__device__ __forceinline__ void gatherB(const float* __restrict__ W, int K, int Nout,
                                        int kbase, int n, short8& hi, short8& lo){
  #pragma unroll
  for (int j = 0; j < 8; ++j){
    int k = kbase + j;
    float w = (k < K && n < Nout) ? W[(size_t)k * Nout + n] : 0.f;
    HL s = split1(w); hi[j] = s.hi; lo[j] = s.lo;
  }
}

// 3-product accurate bf16 MFMA: D += Ah*Bh + Al*Bh + Ah*Bl
__device__ __forceinline__ f32x4 mfma3(short8 ah, short8 al, short8 bh, short8 bl, f32x4 c){
  c = __builtin_amdgcn_mfma_f32_16x16x32_bf16(ah, bh, c, 0, 0, 0);
  c = __builtin_amdgcn_mfma_f32_16x16x32_bf16(al, bh, c, 0, 0, 0);
  c = __builtin_amdgcn_mfma_f32_16x16x32_bf16(ah, bl, c, 0, 0, 0);
  return c;
}

// pre-split stores: split once at producer, consumers ds_read_b128 hi/lo planes directly
__device__ __forceinline__ void sstore1(short* hp, short* lp, int idx, float x){
  HL s = split1(x); hp[idx] = s.hi; lp[idx] = s.lo;
}
__device__ __forceinline__ void sstore4(short* hp, short* lp, int idx, f32x4 v){
  short4v h, l;
  #pragma unroll
  for (int j = 0; j < 4; ++j){ HL s = split1(v[j]); h[j] = s.hi; l[j] = s.lo; }
  *(short4v*)(hp + idx) = h;
  *(short4v*)(lp + idx) = l;
}

// ---- edge kernel LDS geometry (all strides in shorts), 32-edge tile ----
// H2 ALIASES the X region: X dead after bar B (L1 its only reader); H2 born after bar B,
// dead at bar D before the next stage.
#define XS   168            // X rows: 144 real cols + pad to K=160 (pads re-zeroed each stage)
#define H1S  72             // 64-col buffers
#define H2S  136            // 128-col buffer
#define OFF_XL   5376       // Xh @0 (32*168)
#define OFF_H2H  0          // aliases Xh
#define OFF_H2L  4352       // 32*136; [0,8704) inside X region [0,10752)
#define OFF_H1H  10752
#define OFF_H1L  13056      // 32*72=2304
#define OFF_DST  15360      // int dstI[2][32] parity (=128 shorts)
#define LDS_SHORTS 15488
#define LDS_BYTES  (LDS_SHORTS*2)   // 30976 B -> 2 blocks/CU co-resident (reg cap: 8 waves/CU)

// -------- edge kernel: 32 edges/block-tile, 4 waves, weights in regs, 4 barriers/tile --------
// MLP_msg 144->64->128->64->65; gate=sigmoid(col0); cols1..32 *g -> sum, 33..64 *g -> max.
// NOTE: ~192 regs/wave needed -> hard cap 8 waves/CU; do NOT tighten launch_bounds
// (rounds 1&3: forcing more waves spills -> FETCH explodes). The occupancy lever here is
// TWO independent 4-wave blocks per CU = two barrier domains that overlap each other's stalls.
__global__ __launch_bounds__(256, 2) void edge_mfma(
    const float* __restrict__ nf, const float* __restrict__ ef,
    const int* __restrict__ src, const int* __restrict__ dst,
    const float* __restrict__ Wm1, const float* __restrict__ bm1,
    const float* __restrict__ Wm2, const float* __restrict__ bm2,
    const float* __restrict__ Wm3, const float* __restrict__ bm3,
    const float* __restrict__ Wm4, const float* __restrict__ bm4,
    float* __restrict__ nf1, float* __restrict__ nf2, int E)
{
  extern __shared__ short smem[];
  short* Xh  = smem;
  short* Xl  = smem + OFF_XL;
  short* H2h = smem + OFF_H2H;   // alias of X region
  short* H2l = smem + OFF_H2L;
  short* H1h = smem + OFF_H1H;
  short* H1l = smem + OFF_H1L;
  int*  dstI = (int*)(smem + OFF_DST);

  const int lane = threadIdx.x & 63, wv = threadIdx.x >> 6;   // wv = nb1 in 0..3
  const int nl = lane & 15, quad = lane >> 4;
  const int nb1 = wv;
  const int slot = wv*4 + quad;           // 0..15, stages rows slot*2, slot*2+1

  // ---- loop-invariant B fragments (hi/lo bf16) in registers ----
  short8 B1h[5], B1l[5];
  #pragma unroll
  for (int kc = 0; kc < 5; ++kc) gatherB(Wm1, 144, 64,  kc*32 + quad*8, nb1*16 + nl, B1h[kc], B1l[kc]);
  short8 B2h[2][2], B2l[2][2];
  #pragma unroll
  for (int i = 0; i < 2; ++i)
    #pragma unroll
    for (int kc = 0; kc < 2; ++kc) gatherB(Wm2, 64, 128, kc*32 + quad*8, (nb1 + i*4)*16 + nl, B2h[i][kc], B2l[i][kc]);
  short8 B3h[4], B3l[4];
  #pragma unroll
  for (int kc = 0; kc < 4; ++kc) gatherB(Wm3, 128, 64,  kc*32 + quad*8, nb1*16 + nl, B3h[kc], B3l[kc]);
  short8 B4h[2], B4l[2];                  // tileA: cols nb1*16+nl
  #pragma unroll
  for (int kc = 0; kc < 2; ++kc) gatherB(Wm4, 64, 65, kc*32 + quad*8, nb1*16 + nl, B4h[kc], B4l[kc]);
  // gate fragment: lanes 0..7 broadcast col 0 (gate logit), lanes 8..15 broadcast col 64.
  const int gcol = (nl < 8) ? 0 : 64;
  short8 Bgh[2], Bgl[2];
  #pragma unroll
  for (int kc = 0; kc < 2; ++kc) gatherB(Wm4, 64, 65, kc*32 + quad*8, gcol, Bgh[kc], Bgl[kc]);

  const float bi1  = bm1[nb1*16 + nl];
  const float bi2a = bm2[nb1*16 + nl], bi2b = bm2[(nb1+4)*16 + nl];
  const float bi3  = bm3[nb1*16 + nl];
  const float bi4a = bm4[nb1*16 + nl];
  const float big  = bm4[gcol];

  const int ntiles = (E + 31) >> 5;
  int pp = 0;
  for (int t = blockIdx.x; t < ntiles; t += gridDim.x, pp ^= 1){
    // ---- stage X = [nf[src]|nf[dst]|ef|pad0], split once to hi/lo planes ----
    #pragma unroll
    for (int r2 = 0; r2 < 2; ++r2){
      int row = slot*2 + r2;              // 0..31
      int e = (t << 5) + row;
      int ec = e < E ? e : 0;
      int s = src[ec], d = dst[ec];
      f32x4 v0 = *(const f32x4*)(nf + (size_t)s*64 + nl*4);
      f32x4 v1 = *(const f32x4*)(nf + (size_t)d*64 + nl*4);
      sstore4(Xh, Xl, row*XS + nl*4,      v0);
      sstore4(Xh, Xl, row*XS + 64 + nl*4, v1);
      if (nl < 4){
        f32x4 v2 = *(const f32x4*)(ef + (size_t)ec*16 + nl*4);
        sstore4(Xh, Xl, row*XS + 128 + nl*4, v2);
      } else if (nl < 8){
        // re-zero pad cols 144..159 (clobbered by aliased H2 last tile); 0*NaN = NaN in MFMA
        short4v z = {0,0,0,0};
        *(short4v*)(Xh + row*XS + 144 + (nl-4)*4) = z;
        *(short4v*)(Xl + row*XS + 144 + (nl-4)*4) = z;
      }
      if (nl == 5) dstI[pp*32 + row] = (e < E) ? d : -1;
    }
    __syncthreads();   // A: X visible; also drains this wave's prev-tile atomics

    // ---- L1: K=160 (144 real, pads zeroed), X -> H1 ----
    {
      f32x4 a1[2] = {{bi1,bi1,bi1,bi1},{bi1,bi1,bi1,bi1}};
      #pragma unroll
      for (int kc = 0; kc < 5; ++kc)
        #pragma unroll
        for (int mb = 0; mb < 2; ++mb){
          int ro = (mb*16 + nl)*XS + kc*32 + quad*8;
          short8 ah = *(const short8*)(Xh + ro);
          short8 al = *(const short8*)(Xl + ro);
          a1[mb] = mfma3(ah, al, B1h[kc], B1l[kc], a1[mb]);
        }
      #pragma unroll
      for (int mb = 0; mb < 2; ++mb)
        #pragma unroll
        for (int r = 0; r < 4; ++r)
          sstore1(H1h, H1l, (mb*16 + quad*4 + r)*H1S + nb1*16 + nl, lrelu(a1[mb][r]));
    }
    __syncthreads();   // B: all X reads done -> H2 may overwrite X region

    // ---- L2: K=64, dual n-block, H1 -> H2 (aliased over X) ----
    {
      f32x4 a2a[2] = {{bi2a,bi2a,bi2a,bi2a},{bi2a,bi2a,bi2a,bi2a}};
      f32x4 a2b[2] = {{bi2b,bi2b,bi2b,bi2b},{bi2b,bi2b,bi2b,bi2b}};
      #pragma unroll
      for (int kc = 0; kc < 2; ++kc)
        #pragma unroll
        for (int mb = 0; mb < 2; ++mb){
          int ro = (mb*16 + nl)*H1S + kc*32 + quad*8;
          short8 ah = *(const short8*)(H1h + ro);
          short8 al = *(const short8*)(H1l + ro);
          a2a[mb] = mfma3(ah, al, B2h[0][kc], B2l[0][kc], a2a[mb]);
          a2b[mb] = mfma3(ah, al, B2h[1][kc], B2l[1][kc], a2b[mb]);
        }
      #pragma unroll
      for (int mb = 0; mb < 2; ++mb)
        #pragma unroll
        for (int r = 0; r < 4; ++r){
          int row = mb*16 + quad*4 + r;
          sstore1(H2h, H2l, row*H2S + nb1*16 + nl,     lrelu(a2a[mb][r]));
          sstore1(H2h, H2l, row*H2S + (nb1+4)*16 + nl, lrelu(a2b[mb][r]));
        }
    }
    __syncthreads();   // C

    // ---- L3: K=128, H2 -> H1 (all L2 reads of H1 completed at C) ----
    {
      f32x4 a3[2] = {{bi3,bi3,bi3,bi3},{bi3,bi3,bi3,bi3}};
      #pragma unroll
      for (int kc = 0; kc < 4; ++kc)
        #pragma unroll
        for (int mb = 0; mb < 2; ++mb){
          int ro = (mb*16 + nl)*H2S + kc*32 + quad*8;
          short8 ah = *(const short8*)(H2h + ro);
          short8 al = *(const short8*)(H2l + ro);
          a3[mb] = mfma3(ah, al, B3h[kc], B3l[kc], a3[mb]);
        }
      #pragma unroll
      for (int mb = 0; mb < 2; ++mb)
        #pragma unroll
        for (int r = 0; r < 4; ++r)
          sstore1(H1h, H1l, (mb*16 + quad*4 + r)*H1S + nb1*16 + nl, lrelu(a3[mb][r]));
    }
    __syncthreads();   // D: H2 (X region) reads done -> next stage may overwrite

    // ---- L4: K=64, tileA + gate/col64 broadcast frags; scatter (fire-and-forget atomics) ----
    {
      f32x4 a4[2] = {{bi4a,bi4a,bi4a,bi4a},{bi4a,bi4a,bi4a,bi4a}};
      f32x4 ag[2] = {{big,big,big,big},{big,big,big,big}};
      #pragma unroll
      for (int kc = 0; kc < 2; ++kc)
        #pragma unroll
        for (int mb = 0; mb < 2; ++mb){
          int ro = (mb*16 + nl)*H1S + kc*32 + quad*8;
          short8 ah = *(const short8*)(H1h + ro);
          short8 al = *(const short8*)(H1l + ro);
          a4[mb] = mfma3(ah, al, B4h[kc], B4l[kc], a4[mb]);
          ag[mb] = mfma3(ah, al, Bgh[kc], Bgl[kc], ag[mb]);
        }
      const int n = nb1*16 + nl;
      #pragma unroll
      for (int mb = 0; mb < 2; ++mb)
        #pragma unroll
        for (int r = 0; r < 4; ++r){
          int row = mb*16 + quad*4 + r;
          float glog = __shfl(ag[mb][r], lane & 0x30);   // quad's nl==0 lane holds col-0 logit
          float g = 1.f/(1.f + __expf(-glog));
          int d = dstI[pp*32 + row];
          if (d >= 0){
            float v = a4[mb][r] * g;
            if (n >= 1 && n <= 32)  atomicAdd(nf1 + (size_t)d*32 + (n-1), v);
            else if (n >= 33)       atomicMaxF(nf2 + (size_t)d*32 + (n-33), v);
            if (nb1 == 0 && nl == 8)                      // lanes 8..15 hold col-64 output
              atomicMaxF(nf2 + (size_t)d*32 + 31, ag[mb][r] * g);
          }
        }
    }
    // no tail barrier: next stage writes X region (dead since bar D) and dstI[pp^1]
  }
}

__device__ void zero_f(float* p, int n){
  for (int i = threadIdx.x; i < n; i += blockDim.x) p[i] = 0.f;
}

#define B1S 68    // h-buffer stride
#define C0S 132   // node buf0 stride

// RNE split A-chunk (8 f32 from LDS row) -> hi/lo bf16 fragments (node kernel path)
__device__ __forceinline__ void splitA(const float* arow, int k0, short8& hi, short8& lo){
  f32x4 x0 = *(const f32x4*)(arow + k0);
  f32x4 x1 = *(const f32x4*)(arow + k0 + 4);
  #pragma unroll
  for (int j = 0; j < 4; ++j){
    HL a = split1(x0[j]); hi[j]   = a.hi; lo[j]   = a.lo;
    HL b = split1(x1[j]); hi[4+j] = b.hi; lo[4+j] = b.lo;
  }
}

// -------- node kernel: 32 nodes per block-tile, 8 waves (unchanged) --------
__global__ __launch_bounds__(512, 2) void node_mfma(
    const float* __restrict__ nf,
    const float* __restrict__ nf1, const float* __restrict__ nf2,
    const float* __restrict__ Wr1, const float* __restrict__ br1,
    const float* __restrict__ Wr2, const float* __restrict__ br2,
    const float* __restrict__ Wr3, const float* __restrict__ br3,
    const float* __restrict__ Wr4, const float* __restrict__ br4,
    float* __restrict__ out, int N)
{
  __shared__ float buf0[32*C0S];
  __shared__ float buf1[32*B1S];

  zero_f(buf0, 32*C0S);
  zero_f(buf1, 32*B1S);

  const int lane = threadIdx.x & 63, wv = threadIdx.x >> 6;
  const int nl = lane & 15, quad = lane >> 4;
  const int m = wv >> 2, nb = wv & 3;

  short8 B1h[4], B1l[4];
  #pragma unroll
  for (int kc = 0; kc < 4; ++kc) gatherB(Wr1, 128, 64,  kc*32 + quad*8, nb*16 + nl, B1h[kc], B1l[kc]);
  short8 B2h[2][2], B2l[2][2];
  #pragma unroll
  for (int i = 0; i < 2; ++i)
    #pragma unroll
    for (int kc = 0; kc < 2; ++kc) gatherB(Wr2, 64, 128, kc*32 + quad*8, (nb + i*4)*16 + nl, B2h[i][kc], B2l[i][kc]);
  short8 B3h[4], B3l[4];
  #pragma unroll
  for (int kc = 0; kc < 4; ++kc) gatherB(Wr3, 128, 64,  kc*32 + quad*8, nb*16 + nl, B3h[kc], B3l[kc]);
  short8 B4h[2], B4l[2];
  #pragma unroll
  for (int kc = 0; kc < 2; ++kc) gatherB(Wr4, 64, 64,   kc*32 + quad*8, nb*16 + nl, B4h[kc], B4l[kc]);

  const float bi1  = br1[nb*16 + nl];
  const float bi2a = br2[nb*16 + nl], bi2b = br2[(nb+4)*16 + nl];
  const float bi3  = br3[nb*16 + nl];
  const float bi4  = br4[nb*16 + nl];
  __syncthreads();

  const int ntiles = (N + 31) >> 5;
  for (int t = blockIdx.x; t < ntiles; t += gridDim.x){
    const int base = t << 5;
    {
      int row = wv*4 + quad;
      int n = base + row;
      int nc = n < N ? n : 0;
      *(f32x4*)(buf0 + row*C0S + nl*4) = *(const f32x4*)(nf + (size_t)nc*64 + nl*4);
      if (nl < 8){
        *(f32x4*)(buf0 + row*C0S + 64 + nl*4) = *(const f32x4*)(nf1 + (size_t)nc*32 + nl*4);
      } else {
        f32x4 v = *(const f32x4*)(nf2 + (size_t)nc*32 + (nl-8)*4);
        #pragma unroll
        for (int j = 0; j < 4; ++j) if (!(v[j] >= -3.0e38f)) v[j] = 0.f;  // -inf/NaN -> 0
        *(f32x4*)(buf0 + row*C0S + 96 + (nl-8)*4) = v;
      }
    }
    __syncthreads();

    f32x4 a1 = {bi1, bi1, bi1, bi1};
    {
      const float* arow = buf0 + (m*16 + nl)*C0S;
      #pragma unroll
      for (int kc = 0; kc < 4; ++kc){
        short8 ah, al; splitA(arow, kc*32 + quad*8, ah, al);
        a1 = mfma3(ah, al, B1h[kc], B1l[kc], a1);
      }
    }
    #pragma unroll
    for (int r = 0; r < 4; ++r)
      buf1[(m*16 + quad*4 + r)*B1S + nb*16 + nl] = lrelu(a1[r]);
    __syncthreads();

    f32x4 a2a = {bi2a, bi2a, bi2a, bi2a}, a2b = {bi2b, bi2b, bi2b, bi2b};
    {
      const float* arow = buf1 + (m*16 + nl)*B1S;
      #pragma unroll
      for (int kc = 0; kc < 2; ++kc){
        short8 ah, al; splitA(arow, kc*32 + quad*8, ah, al);
        a2a = mfma3(ah, al, B2h[0][kc], B2l[0][kc], a2a);
        a2b = mfma3(ah, al, B2h[1][kc], B2l[1][kc], a2b);
      }
    }
    #pragma unroll
    for (int r = 0; r < 4; ++r){
      buf0[(m*16 + quad*4 + r)*C0S + nb*16 + nl]     = lrelu(a2a[r]);
      buf0[(m*16 + quad*4 + r)*C0S + (nb+4)*16 + nl] = lrelu(a2b[r]);
    }
    __syncthreads();

    f32x4 a3 = {bi3, bi3, bi3, bi3};
    {
      const float* arow = buf0 + (m*16 + nl)*C0S;
      #pragma unroll
      for (int kc = 0; kc < 4; ++kc){
        short8 ah, al; splitA(arow, kc*32 + quad*8, ah, al);
        a3 = mfma3(ah, al, B3h[kc], B3l[kc], a3);
      }
    }
    #pragma unroll
    for (int r = 0; r < 4; ++r)
      buf1[(m*16 + quad*4 + r)*B1S + nb*16 + nl] = lrelu(a3[r]);
    __syncthreads();

    f32x4 a4 = {bi4, bi4, bi4, bi4};
    {
      const float* arow = buf1 + (m*16 + nl)*B1S;
      #pragma unroll
      for (int kc = 0; kc < 2; ++kc){
        short8 ah, al; splitA(arow, kc*32 + quad*8, ah, al);
        a4 = mfma3(ah, al, B4h[kc], B4l[kc], a4);
      }
    }
    #pragma unroll
    for (int r = 0; r < 4; ++r){
      int n = base + m*16 + quad*4 + r;
      if (n < N) out[(size_t)n*64 + nb*16 + nl] = a4[r];
    }
  }
}

extern "C" void kernel_launch(void* const* d_in, const int* in_sizes, int n_in,
                              void* d_out, int out_size, void* d_ws, size_t ws_size,
                              hipStream_t stream) {
  const float* nf  = (const float*)d_in[0];
  const float* ef  = (const float*)d_in[1];
  const int*   src = (const int*)d_in[2];
  const int*   dst = (const int*)d_in[3];

  const int N = in_sizes[0] / 64;
  const int E = in_sizes[2];

  float* nf1 = (float*)d_ws;               // [N,32] segment-sum
  float* nf2 = nf1 + (size_t)N * 32;       // [N,32] segment-max

  static bool attr_set = false;
  if (!attr_set){
    hipFuncSetAttribute((const void*)edge_mfma,
                        hipFuncAttributeMaxDynamicSharedMemorySize, LDS_BYTES);
    attr_set = true;
  }

  init_ws<<<2048, 256, 0, stream>>>(nf1, nf2, N * 32);

  edge_mfma<<<2048, 256, LDS_BYTES, stream>>>(
      nf, ef, src, dst,
      (const float*)d_in[4],  (const float*)d_in[5],  (const float*)d_in[6],  (const float*)d_in[7],
      (const float*)d_in[8],  (const float*)d_in[9],  (const float*)d_in[10], (const float*)d_in[11],
      nf1, nf2, E);

  node_mfma<<<512, 512, 0, stream>>>(
      nf, nf1, nf2,
      (const float*)d_in[12], (const float*)d_in[13], (const float*)d_in[14], (const float*)d_in[15],
      (const float*)d_in[16], (const float*)d_in[17], (const float*)d_in[18], (const float*)d_in[19],
      (float*)d_out, N);
}

// Round 6
// 1125.808 us; speedup vs baseline: 1.3203x; 1.0040x over previous
//
#include <hip/hip_runtime.h>

typedef unsigned int u32;
typedef __attribute__((ext_vector_type(8))) short short8;
typedef __attribute__((ext_vector_type(4))) short short4v;
typedef __attribute__((ext_vector_type(4))) float f32x4;

__device__ __forceinline__ float lrelu(float x){ return x > 0.f ? x : 0.2f*x; }

// float atomic max via sign-split (dest init -inf)
__device__ __forceinline__ void atomicMaxF(float* a, float v){
  if (__float_as_int(v) >= 0) atomicMax((int*)a, __float_as_int(v));
  else                        atomicMin((u32*)a, __float_as_uint(v));
}

__global__ void init_ws(float* __restrict__ nf1, float* __restrict__ nf2, int n32){
  int i = blockIdx.x*blockDim.x + threadIdx.x;
  int st = gridDim.x*blockDim.x;
  for (; i < n32; i += st){ nf1[i] = 0.f; nf2[i] = -__builtin_inff(); }
}

// RNE split: x = bf16(hi) + bf16(lo) + O(2^-18 x).
struct HL { short hi, lo; };
__device__ __forceinline__ HL split1(float x){
  u32 u = __float_as_uint(x);
  u32 r = u + 0x7FFFu + ((u >> 16) & 1u);
  float l = x - __uint_as_float(r & 0xFFFF0000u);
  HL o; o.hi = (short)(r >> 16); o.lo = (short)(__float_as_uint(l) >> 16);
  return o;
}

// one-time gather of a B fragment (W row-major [K][Nout], f32) with zero-fill OOB
__device__ __forceinline__ void gatherB(const float* __restrict__ W, int K, int Nout,
                                        int kbase, int n, short8& hi, short8& lo){
  #pragma unroll
  for (int j = 0; j < 8; ++j){
    int k = kbase + j;
    float w = (k < K && n < Nout) ? W[(size_t)k * Nout + n] : 0.f;
    HL s = split1(w); hi[j] = s.hi; lo[j] = s.lo;
  }
}

// 3-product accurate bf16 MFMA: D += Ah*Bh + Al*Bh + Ah*Bl
__device__ __forceinline__ f32x4 mfma3(short8 ah, short8 al, short8 bh, short8 bl, f32x4 c){
  c = __builtin_amdgcn_mfma_f32_16x16x32_bf16(ah, bh, c, 0, 0, 0);
  c = __builtin_amdgcn_mfma_f32_16x16x32_bf16(al, bh, c, 0, 0, 0);
  c = __builtin_amdgcn_mfma_f32_16x16x32_bf16(ah, bl, c, 0, 0, 0);
  return c;
}

// pre-split stores: split once at producer, consumers ds_read_b128 hi/lo planes directly
__device__ __forceinline__ void sstore1(short* hp, short* lp, int idx, float x){
  HL s = split1(x); hp[idx] = s.hi; lp[idx] = s.lo;
}
__device__ __forceinline__ void sstore4(short* hp, short* lp, int idx, f32x4 v){
  short4v h, l;
  #pragma unroll
  for (int j = 0; j < 4; ++j){ HL s = split1(v[j]); h[j] = s.hi; l[j] = s.lo; }
  *(short4v*)(hp + idx) = h;
  *(short4v*)(lp + idx) = l;
}

// ---------------- node_pre: P[n] = [ nf[n]·Wm1[0:64] | nf[n]·Wm1[64:128] ] (f32) ----------
// Moves 128 of L1's 144 K-columns from per-edge (1.6M) to per-node (50K) work.
__global__ __launch_bounds__(256, 2) void node_pre(
    const float* __restrict__ nf, const float* __restrict__ Wm1,
    float* __restrict__ P, int N)
{
  __shared__ short Xnh[32*72];
  __shared__ short Xnl[32*72];

  const int lane = threadIdx.x & 63, wv = threadIdx.x >> 6;
  const int nl = lane & 15, quad = lane >> 4;
  const int nb = wv;                      // col block 0..3
  const int slot = wv*4 + quad;           // 0..15

  short8 Bah[2], Bal[2], Bbh[2], Bbl[2];
  #pragma unroll
  for (int kc = 0; kc < 2; ++kc){
    gatherB(Wm1, 144, 64, kc*32 + quad*8,      nb*16 + nl, Bah[kc], Bal[kc]);  // src rows 0..63
    gatherB(Wm1, 144, 64, 64 + kc*32 + quad*8, nb*16 + nl, Bbh[kc], Bbl[kc]);  // dst rows 64..127
  }

  const int ntiles = (N + 31) >> 5;
  for (int t = blockIdx.x; t < ntiles; t += gridDim.x){
    const int base = t << 5;
    #pragma unroll
    for (int r2 = 0; r2 < 2; ++r2){
      int row = slot*2 + r2;
      int n = base + row;
      int nc = n < N ? n : 0;
      f32x4 v = *(const f32x4*)(nf + (size_t)nc*64 + nl*4);
      sstore4(Xnh, Xnl, row*72 + nl*4, v);
    }
    __syncthreads();

    f32x4 aa[2] = {{0,0,0,0},{0,0,0,0}};
    f32x4 ab[2] = {{0,0,0,0},{0,0,0,0}};
    #pragma unroll
    for (int kc = 0; kc < 2; ++kc)
      #pragma unroll
      for (int mb = 0; mb < 2; ++mb){
        int ro = (mb*16 + nl)*72 + kc*32 + quad*8;
        short8 ah = *(const short8*)(Xnh + ro);
        short8 al = *(const short8*)(Xnl + ro);
        aa[mb] = mfma3(ah, al, Bah[kc], Bal[kc], aa[mb]);
        ab[mb] = mfma3(ah, al, Bbh[kc], Bbl[kc], ab[mb]);
      }
    #pragma unroll
    for (int mb = 0; mb < 2; ++mb)
      #pragma unroll
      for (int r = 0; r < 4; ++r){
        int n = base + mb*16 + quad*4 + r;
        if (n < N){
          P[(size_t)n*128 +      nb*16 + nl] = aa[mb][r];
          P[(size_t)n*128 + 64 + nb*16 + nl] = ab[mb][r];
        }
      }
    __syncthreads();   // Xn reuse
  }
}

// ---- P-path edge kernel LDS geometry (shorts unless noted) ----
#define PXES  40            // ef planes: 16 real cols + 16 zero-pad (+slack), rows 16B-aligned
#define PSS   68            // S buffer stride in f32
#define PH1S  72
#define PH2S  136
#define POFF_XEL  1280      // Xeh @0 (32*40)
#define POFF_S    2560      // f32 S[32][68] = 4352 shorts
#define POFF_H1H  6912
#define POFF_H1L  9216
#define POFF_H2H  11520
#define POFF_H2L  15872
#define POFF_DST  20224     // int dstI[2][32]
#define P_LDS_SHORTS 20352
#define P_LDS_BYTES  (P_LDS_SHORTS*2)   // 40704 B -> 2 blocks/CU (reg cap: 8 waves/CU)

// -------- P-path edge kernel: 32 edges/tile, 4 waves, L1 reduced to ef-only K=32 --------
// h1 = lrelu( S + ef·W1c + b1 ), S = P[src][0:64] + P[dst][64:128] staged in f32.
// NOTE: ~250 unified regs/wave -> hard cap 8 waves/CU; never tighten launch_bounds
// (rounds 1&3: forcing more waves spills -> FETCH explodes).
__global__ __launch_bounds__(256, 2) void edge_mfma_p(
    const float* __restrict__ P, const float* __restrict__ ef,
    const int* __restrict__ src, const int* __restrict__ dst,
    const float* __restrict__ Wm1, const float* __restrict__ bm1,
    const float* __restrict__ Wm2, const float* __restrict__ bm2,
    const float* __restrict__ Wm3, const float* __restrict__ bm3,
    const float* __restrict__ Wm4, const float* __restrict__ bm4,
    float* __restrict__ nf1, float* __restrict__ nf2, int E)
{
  extern __shared__ short smem[];
  short* Xeh = smem;
  short* Xel = smem + POFF_XEL;
  float* Sb  = (float*)(smem + POFF_S);
  short* H1h = smem + POFF_H1H;
  short* H1l = smem + POFF_H1L;
  short* H2h = smem + POFF_H2H;
  short* H2l = smem + POFF_H2L;
  int*  dstI = (int*)(smem + POFF_DST);

  // one-time zero of ef planes (pads 16..31 must stay 0; no aliasing -> zero once)
  {
    float* z = (float*)smem;
    for (int i = threadIdx.x; i < POFF_XEL; i += blockDim.x) z[i] = 0.f;  // 2*1280 shorts
  }

  const int lane = threadIdx.x & 63, wv = threadIdx.x >> 6;
  const int nl = lane & 15, quad = lane >> 4;
  const int nb1 = wv;
  const int slot = wv*4 + quad;

  // ---- loop-invariant B fragments ----
  short8 B1ch, B1cl;                      // ef block: Wm1 rows 128..143 (zero-filled past 144)
  gatherB(Wm1, 144, 64, 128 + quad*8, nb1*16 + nl, B1ch, B1cl);
  short8 B2h[2][2], B2l[2][2];
  #pragma unroll
  for (int i = 0; i < 2; ++i)
    #pragma unroll
    for (int kc = 0; kc < 2; ++kc) gatherB(Wm2, 64, 128, kc*32 + quad*8, (nb1 + i*4)*16 + nl, B2h[i][kc], B2l[i][kc]);
  short8 B3h[4], B3l[4];
  #pragma unroll
  for (int kc = 0; kc < 4; ++kc) gatherB(Wm3, 128, 64,  kc*32 + quad*8, nb1*16 + nl, B3h[kc], B3l[kc]);
  short8 B4h[2], B4l[2];
  #pragma unroll
  for (int kc = 0; kc < 2; ++kc) gatherB(Wm4, 64, 65, kc*32 + quad*8, nb1*16 + nl, B4h[kc], B4l[kc]);
  const int gcol = (nl < 8) ? 0 : 64;     // gate col 0 / col 64 broadcast
  short8 Bgh[2], Bgl[2];
  #pragma unroll
  for (int kc = 0; kc < 2; ++kc) gatherB(Wm4, 64, 65, kc*32 + quad*8, gcol, Bgh[kc], Bgl[kc]);

  const float bi1  = bm1[nb1*16 + nl];
  const float bi2a = bm2[nb1*16 + nl], bi2b = bm2[(nb1+4)*16 + nl];
  const float bi3  = bm3[nb1*16 + nl];
  const float bi4a = bm4[nb1*16 + nl];
  const float big  = bm4[gcol];
  __syncthreads();   // ef-plane zeros visible

  const int ntiles = (E + 31) >> 5;
  int pp = 0;
  for (int t = blockIdx.x; t < ntiles; t += gridDim.x, pp ^= 1){
    // ---- stage: S = P[src]+P[dst-half] (f32, b128 writes); ef split to planes ----
    #pragma unroll
    for (int r2 = 0; r2 < 2; ++r2){
      int row = slot*2 + r2;              // 0..31
      int e = (t << 5) + row;
      int ec = e < E ? e : 0;
      int s = src[ec], d = dst[ec];
      f32x4 a = *(const f32x4*)(P + (size_t)s*128 +      nl*4);
      f32x4 b = *(const f32x4*)(P + (size_t)d*128 + 64 + nl*4);
      f32x4 sv = a + b;
      *(f32x4*)(Sb + row*PSS + nl*4) = sv;
      if (nl < 4){
        f32x4 v2 = *(const f32x4*)(ef + (size_t)ec*16 + nl*4);
        sstore4(Xeh, Xel, row*PXES + nl*4, v2);
      }
      if (nl == 5) dstI[pp*32 + row] = (e < E) ? d : -1;
    }
    __syncthreads();   // A: S/Xe visible; drains prev-tile atomics + P gathers

    // ---- L1: K=32 (16 real ef cols), + S epilogue add -> H1 ----
    {
      f32x4 a1[2] = {{bi1,bi1,bi1,bi1},{bi1,bi1,bi1,bi1}};
      #pragma unroll
      for (int mb = 0; mb < 2; ++mb){
        int ro = (mb*16 + nl)*PXES + quad*8;
        short8 ah = *(const short8*)(Xeh + ro);
        short8 al = *(const short8*)(Xel + ro);
        a1[mb] = mfma3(ah, al, B1ch, B1cl, a1[mb]);
      }
      #pragma unroll
      for (int mb = 0; mb < 2; ++mb)
        #pragma unroll
        for (int r = 0; r < 4; ++r){
          int row = mb*16 + quad*4 + r;
          float sv = Sb[row*PSS + nb1*16 + nl];
          sstore1(H1h, H1l, row*PH1S + nb1*16 + nl, lrelu(a1[mb][r] + sv));
        }
    }
    __syncthreads();   // B

    // ---- L2: K=64, dual n-block, H1 -> H2 ----
    {
      f32x4 a2a[2] = {{bi2a,bi2a,bi2a,bi2a},{bi2a,bi2a,bi2a,bi2a}};
      f32x4 a2b[2] = {{bi2b,bi2b,bi2b,bi2b},{bi2b,bi2b,bi2b,bi2b}};
      #pragma unroll
      for (int kc = 0; kc < 2; ++kc)
        #pragma unroll
        for (int mb = 0; mb < 2; ++mb){
          int ro = (mb*16 + nl)*PH1S + kc*32 + quad*8;
          short8 ah = *(const short8*)(H1h + ro);
          short8 al = *(const short8*)(H1l + ro);
          a2a[mb] = mfma3(ah, al, B2h[0][kc], B2l[0][kc], a2a[mb]);
          a2b[mb] = mfma3(ah, al, B2h[1][kc], B2l[1][kc], a2b[mb]);
        }
      #pragma unroll
      for (int mb = 0; mb < 2; ++mb)
        #pragma unroll
        for (int r = 0; r < 4; ++r){
          int row = mb*16 + quad*4 + r;
          sstore1(H2h, H2l, row*PH2S + nb1*16 + nl,     lrelu(a2a[mb][r]));
          sstore1(H2h, H2l, row*PH2S + (nb1+4)*16 + nl, lrelu(a2b[mb][r]));
        }
    }
    __syncthreads();   // C

    // ---- L3: K=128, H2 -> H1 ----
    {
      f32x4 a3[2] = {{bi3,bi3,bi3,bi3},{bi3,bi3,bi3,bi3}};
      #pragma unroll
      for (int kc = 0; kc < 4; ++kc)
        #pragma unroll
        for (int mb = 0; mb < 2; ++mb){
          int ro = (mb*16 + nl)*PH2S + kc*32 + quad*8;
          short8 ah = *(const short8*)(H2h + ro);
          short8 al = *(const short8*)(H2l + ro);
          a3[mb] = mfma3(ah, al, B3h[kc], B3l[kc], a3[mb]);
        }
      #pragma unroll
      for (int mb = 0; mb < 2; ++mb)
        #pragma unroll
        for (int r = 0; r < 4; ++r)
          sstore1(H1h, H1l, (mb*16 + quad*4 + r)*PH1S + nb1*16 + nl, lrelu(a3[mb][r]));
    }
    __syncthreads();   // D

    // ---- L4 + scatter ----
    {
      f32x4 a4[2] = {{bi4a,bi4a,bi4a,bi4a},{bi4a,bi4a,bi4a,bi4a}};
      f32x4 ag[2] = {{big,big,big,big},{big,big,big,big}};
      #pragma unroll
      for (int kc = 0; kc < 2; ++kc)
        #pragma unroll
        for (int mb = 0; mb < 2; ++mb){
          int ro = (mb*16 + nl)*PH1S + kc*32 + quad*8;
          short8 ah = *(const short8*)(H1h + ro);
          short8 al = *(const short8*)(H1l + ro);
          a4[mb] = mfma3(ah, al, B4h[kc], B4l[kc], a4[mb]);
          ag[mb] = mfma3(ah, al, Bgh[kc], Bgl[kc], ag[mb]);
        }
      const int n = nb1*16 + nl;
      #pragma unroll
      for (int mb = 0; mb < 2; ++mb)
        #pragma unroll
        for (int r = 0; r < 4; ++r){
          int row = mb*16 + quad*4 + r;
          float glog = __shfl(ag[mb][r], lane & 0x30);
          float g = 1.f/(1.f + __expf(-glog));
          int d = dstI[pp*32 + row];
          if (d >= 0){
            float v = a4[mb][r] * g;
            if (n >= 1 && n <= 32)  atomicAdd(nf1 + (size_t)d*32 + (n-1), v);
            else if (n >= 33)       atomicMaxF(nf2 + (size_t)d*32 + (n-33), v);
            if (nb1 == 0 && nl == 8)
              atomicMaxF(nf2 + (size_t)d*32 + 31, ag[mb][r] * g);
          }
        }
    }
    // no tail barrier: next stage writes S/Xe/dstI[pp^1], none read by L4
  }
}

// ---------------- fallback edge kernel (round-5, proven ~1000µs) -------------------------
#define XS   168
#define H1S  72
#define H2S  136
#define OFF_XL   5376
#define OFF_H2H  0
#define OFF_H2L  4352
#define OFF_H1H  10752
#define OFF_H1L  13056
#define OFF_DST  15360
#define LDS_SHORTS 15488
#define LDS_BYTES  (LDS_SHORTS*2)

__global__ __launch_bounds__(256, 2) void edge_mfma(
    const float* __restrict__ nf, const float* __restrict__ ef,
    const int* __restrict__ src, const int* __restrict__ dst,
    const float* __restrict__ Wm1, const float* __restrict__ bm1,
    const float* __restrict__ Wm2, const float* __restrict__ bm2,
    const float* __restrict__ Wm3, const float* __restrict__ bm3,
    const float* __restrict__ Wm4, const float* __restrict__ bm4,
    float* __restrict__ nf1, float* __restrict__ nf2, int E)
{
  extern __shared__ short smem[];
  short* Xh  = smem;
  short* Xl  = smem + OFF_XL;
  short* H2h = smem + OFF_H2H;
  short* H2l = smem + OFF_H2L;
  short* H1h = smem + OFF_H1H;
  short* H1l = smem + OFF_H1L;
  int*  dstI = (int*)(smem + OFF_DST);

  const int lane = threadIdx.x & 63, wv = threadIdx.x >> 6;
  const int nl = lane & 15, quad = lane >> 4;
  const int nb1 = wv;
  const int slot = wv*4 + quad;

  short8 B1h[5], B1l[5];
  #pragma unroll
  for (int kc = 0; kc < 5; ++kc) gatherB(Wm1, 144, 64,  kc*32 + quad*8, nb1*16 + nl, B1h[kc], B1l[kc]);
  short8 B2h[2][2], B2l[2][2];
  #pragma unroll
  for (int i = 0; i < 2; ++i)
    #pragma unroll
    for (int kc = 0; kc < 2; ++kc) gatherB(Wm2, 64, 128, kc*32 + quad*8, (nb1 + i*4)*16 + nl, B2h[i][kc], B2l[i][kc]);
  short8 B3h[4], B3l[4];
  #pragma unroll
  for (int kc = 0; kc < 4; ++kc) gatherB(Wm3, 128, 64,  kc*32 + quad*8, nb1*16 + nl, B3h[kc], B3l[kc]);
  short8 B4h[2], B4l[2];
  #pragma unroll
  for (int kc = 0; kc < 2; ++kc) gatherB(Wm4, 64, 65, kc*32 + quad*8, nb1*16 + nl, B4h[kc], B4l[kc]);
  const int gcol = (nl < 8) ? 0 : 64;
  short8 Bgh[2], Bgl[2];
  #pragma unroll
  for (int kc = 0; kc < 2; ++kc) gatherB(Wm4, 64, 65, kc*32 + quad*8, gcol, Bgh[kc], Bgl[kc]);

  const float bi1  = bm1[nb1*16 + nl];
  const float bi2a = bm2[nb1*16 + nl], bi2b = bm2[(nb1+4)*16 + nl];
  const float bi3  = bm3[nb1*16 + nl];
  const float bi4a = bm4[nb1*16 + nl];
  const float big  = bm4[gcol];

  const int ntiles = (E + 31) >> 5;
  int pp = 0;
  for (int t = blockIdx.x; t < ntiles; t += gridDim.x, pp ^= 1){
    #pragma unroll
    for (int r2 = 0; r2 < 2; ++r2){
      int row = slot*2 + r2;
      int e = (t << 5) + row;
      int ec = e < E ? e : 0;
      int s = src[ec], d = dst[ec];
      f32x4 v0 = *(const f32x4*)(nf + (size_t)s*64 + nl*4);
      f32x4 v1 = *(const f32x4*)(nf + (size_t)d*64 + nl*4);
      sstore4(Xh, Xl, row*XS + nl*4,      v0);
      sstore4(Xh, Xl, row*XS + 64 + nl*4, v1);
      if (nl < 4){
        f32x4 v2 = *(const f32x4*)(ef + (size_t)ec*16 + nl*4);
        sstore4(Xh, Xl, row*XS + 128 + nl*4, v2);
      } else if (nl < 8){
        short4v z = {0,0,0,0};
        *(short4v*)(Xh + row*XS + 144 + (nl-4)*4) = z;
        *(short4v*)(Xl + row*XS + 144 + (nl-4)*4) = z;
      }
      if (nl == 5) dstI[pp*32 + row] = (e < E) ? d : -1;
    }
    __syncthreads();

    {
      f32x4 a1[2] = {{bi1,bi1,bi1,bi1},{bi1,bi1,bi1,bi1}};
      #pragma unroll
      for (int kc = 0; kc < 5; ++kc)
        #pragma unroll
        for (int mb = 0; mb < 2; ++mb){
          int ro = (mb*16 + nl)*XS + kc*32 + quad*8;
          short8 ah = *(const short8*)(Xh + ro);
          short8 al = *(const short8*)(Xl + ro);
          a1[mb] = mfma3(ah, al, B1h[kc], B1l[kc], a1[mb]);
        }
      #pragma unroll
      for (int mb = 0; mb < 2; ++mb)
        #pragma unroll
        for (int r = 0; r < 4; ++r)
          sstore1(H1h, H1l, (mb*16 + quad*4 + r)*H1S + nb1*16 + nl, lrelu(a1[mb][r]));
    }
    __syncthreads();

    {
      f32x4 a2a[2] = {{bi2a,bi2a,bi2a,bi2a},{bi2a,bi2a,bi2a,bi2a}};
      f32x4 a2b[2] = {{bi2b,bi2b,bi2b,bi2b},{bi2b,bi2b,bi2b,bi2b}};
      #pragma unroll
      for (int kc = 0; kc < 2; ++kc)
        #pragma unroll
        for (int mb = 0; mb < 2; ++mb){
          int ro = (mb*16 + nl)*H1S + kc*32 + quad*8;
          short8 ah = *(const short8*)(H1h + ro);
          short8 al = *(const short8*)(H1l + ro);
          a2a[mb] = mfma3(ah, al, B2h[0][kc], B2l[0][kc], a2a[mb]);
          a2b[mb] = mfma3(ah, al, B2h[1][kc], B2l[1][kc], a2b[mb]);
        }
      #pragma unroll
      for (int mb = 0; mb < 2; ++mb)
        #pragma unroll
        for (int r = 0; r < 4; ++r){
          int row = mb*16 + quad*4 + r;
          sstore1(H2h, H2l, row*H2S + nb1*16 + nl,     lrelu(a2a[mb][r]));
          sstore1(H2h, H2l, row*H2S + (nb1+4)*16 + nl, lrelu(a2b[mb][r]));
        }
    }
    __syncthreads();

    {
      f32x4 a3[2] = {{bi3,bi3,bi3,bi3},{bi3,bi3,bi3,bi3}};
      #pragma unroll
      for (int kc = 0; kc < 4; ++kc)
        #pragma unroll
        for (int mb = 0; mb < 2; ++mb){
          int ro = (mb*16 + nl)*H2S + kc*32 + quad*8;
          short8 ah = *(const short8*)(H2h + ro);
          short8 al = *(const short8*)(H2l + ro);
          a3[mb] = mfma3(ah, al, B3h[kc], B3l[kc], a3[mb]);
        }
      #pragma unroll
      for (int mb = 0; mb < 2; ++mb)
        #pragma unroll
        for (int r = 0; r < 4; ++r)
          sstore1(H1h, H1l, (mb*16 + quad*4 + r)*H1S + nb1*16 + nl, lrelu(a3[mb][r]));
    }
    __syncthreads();

    {
      f32x4 a4[2] = {{bi4a,bi4a,bi4a,bi4a},{bi4a,bi4a,bi4a,bi4a}};
      f32x4 ag[2] = {{big,big,big,big},{big,big,big,big}};
      #pragma unroll
      for (int kc = 0; kc < 2; ++kc)
        #pragma unroll
        for (int mb = 0; mb < 2; ++mb){
          int ro = (mb*16 + nl)*H1S + kc*32 + quad*8;
          short8 ah = *(const short8*)(H1h + ro);
          short8 al = *(const short8*)(H1l + ro);
          a4[mb] = mfma3(ah, al, B4h[kc], B4l[kc], a4[mb]);
          ag[mb] = mfma3(ah, al, Bgh[kc], Bgl[kc], ag[mb]);
        }
      const int n = nb1*16 + nl;
      #pragma unroll
      for (int mb = 0; mb < 2; ++mb)
        #pragma unroll
        for (int r = 0; r < 4; ++r){
          int row = mb*16 + quad*4 + r;
          float glog = __shfl(ag[mb][r], lane & 0x30);
          float g = 1.f/(1.f + __expf(-glog));
          int d = dstI[pp*32 + row];
          if (d >= 0){
            float v = a4[mb][r] * g;
            if (n >= 1 && n <= 32)  atomicAdd(nf1 + (size_t)d*32 + (n-1), v);
            else if (n >= 33)       atomicMaxF(nf2 + (size_t)d*32 + (n-33), v);
            if (nb1 == 0 && nl == 8)
              atomicMaxF(nf2 + (size_t)d*32 + 31, ag[mb][r] * g);
          }
        }
    }
  }
}

__device__ void zero_f(float* p, int n){
  for (int i = threadIdx.x; i < n; i += blockDim.x) p[i] = 0.f;
}

#define B1S 68
#define C0S 132

__device__ __forceinline__ void splitA(const float* arow, int k0, short8& hi, short8& lo){
  f32x4 x0 = *(const f32x4*)(arow + k0);
  f32x4 x1 = *(const f32x4*)(arow + k0 + 4);
  #pragma unroll
  for (int j = 0; j < 4; ++j){
    HL a = split1(x0[j]); hi[j]   = a.hi; lo[j]   = a.lo;
    HL b = split1(x1[j]); hi[4+j] = b.hi; lo[4+j] = b.lo;
  }
}

// -------- node kernel: 32 nodes per block-tile, 8 waves (unchanged) --------
__global__ __launch_bounds__(512, 2) void node_mfma(
    const float* __restrict__ nf,
    const float* __restrict__ nf1, const float* __restrict__ nf2,
    const float* __restrict__ Wr1, const float* __restrict__ br1,
    const float* __restrict__ Wr2, const float* __restrict__ br2,
    const float* __restrict__ Wr3, const float* __restrict__ br3,
    const float* __restrict__ Wr4, const float* __restrict__ br4,
    float* __restrict__ out, int N)
{
  __shared__ float buf0[32*C0S];
  __shared__ float buf1[32*B1S];

  zero_f(buf0, 32*C0S);
  zero_f(buf1, 32*B1S);

  const int lane = threadIdx.x & 63, wv = threadIdx.x >> 6;
  const int nl = lane & 15, quad = lane >> 4;
  const int m = wv >> 2, nb = wv & 3;

  short8 B1h[4], B1l[4];
  #pragma unroll
  for (int kc = 0; kc < 4; ++kc) gatherB(Wr1, 128, 64,  kc*32 + quad*8, nb*16 + nl, B1h[kc], B1l[kc]);
  short8 B2h[2][2], B2l[2][2];
  #pragma unroll
  for (int i = 0; i < 2; ++i)
    #pragma unroll
    for (int kc = 0; kc < 2; ++kc) gatherB(Wr2, 64, 128, kc*32 + quad*8, (nb + i*4)*16 + nl, B2h[i][kc], B2l[i][kc]);
  short8 B3h[4], B3l[4];
  #pragma unroll
  for (int kc = 0; kc < 4; ++kc) gatherB(Wr3, 128, 64,  kc*32 + quad*8, nb*16 + nl, B3h[kc], B3l[kc]);
  short8 B4h[2], B4l[2];
  #pragma unroll
  for (int kc = 0; kc < 2; ++kc) gatherB(Wr4, 64, 64,   kc*32 + quad*8, nb*16 + nl, B4h[kc], B4l[kc]);

  const float bi1  = br1[nb*16 + nl];
  const float bi2a = br2[nb*16 + nl], bi2b = br2[(nb+4)*16 + nl];
  const float bi3  = br3[nb*16 + nl];
  const float bi4  = br4[nb*16 + nl];
  __syncthreads();

  const int ntiles = (N + 31) >> 5;
  for (int t = blockIdx.x; t < ntiles; t += gridDim.x){
    const int base = t << 5;
    {
      int row = wv*4 + quad;
      int n = base + row;
      int nc = n < N ? n : 0;
      *(f32x4*)(buf0 + row*C0S + nl*4) = *(const f32x4*)(nf + (size_t)nc*64 + nl*4);
      if (nl < 8){
        *(f32x4*)(buf0 + row*C0S + 64 + nl*4) = *(const f32x4*)(nf1 + (size_t)nc*32 + nl*4);
      } else {
        f32x4 v = *(const f32x4*)(nf2 + (size_t)nc*32 + (nl-8)*4);
        #pragma unroll
        for (int j = 0; j < 4; ++j) if (!(v[j] >= -3.0e38f)) v[j] = 0.f;
        *(f32x4*)(buf0 + row*C0S + 96 + (nl-8)*4) = v;
      }
    }
    __syncthreads();

    f32x4 a1 = {bi1, bi1, bi1, bi1};
    {
      const float* arow = buf0 + (m*16 + nl)*C0S;
      #pragma unroll
      for (int kc = 0; kc < 4; ++kc){
        short8 ah, al; splitA(arow, kc*32 + quad*8, ah, al);
        a1 = mfma3(ah, al, B1h[kc], B1l[kc], a1);
      }
    }
    #pragma unroll
    for (int r = 0; r < 4; ++r)
      buf1[(m*16 + quad*4 + r)*B1S + nb*16 + nl] = lrelu(a1[r]);
    __syncthreads();

    f32x4 a2a = {bi2a, bi2a, bi2a, bi2a}, a2b = {bi2b, bi2b, bi2b, bi2b};
    {
      const float* arow = buf1 + (m*16 + nl)*B1S;
      #pragma unroll
      for (int kc = 0; kc < 2; ++kc){
        short8 ah, al; splitA(arow, kc*32 + quad*8, ah, al);
        a2a = mfma3(ah, al, B2h[0][kc], B2l[0][kc], a2a);
        a2b = mfma3(ah, al, B2h[1][kc], B2l[1][kc], a2b);
      }
    }
    #pragma unroll
    for (int r = 0; r < 4; ++r){
      buf0[(m*16 + quad*4 + r)*C0S + nb*16 + nl]     = lrelu(a2a[r]);
      buf0[(m*16 + quad*4 + r)*C0S + (nb+4)*16 + nl] = lrelu(a2b[r]);
    }
    __syncthreads();

    f32x4 a3 = {bi3, bi3, bi3, bi3};
    {
      const float* arow = buf0 + (m*16 + nl)*C0S;
      #pragma unroll
      for (int kc = 0; kc < 4; ++kc){
        short8 ah, al; splitA(arow, kc*32 + quad*8, ah, al);
        a3 = mfma3(ah, al, B3h[kc], B3l[kc], a3);
      }
    }
    #pragma unroll
    for (int r = 0; r < 4; ++r)
      buf1[(m*16 + quad*4 + r)*B1S + nb*16 + nl] = lrelu(a3[r]);
    __syncthreads();

    f32x4 a4 = {bi4, bi4, bi4, bi4};
    {
      const float* arow = buf1 + (m*16 + nl)*B1S;
      #pragma unroll
      for (int kc = 0; kc < 2; ++kc){
        short8 ah, al; splitA(arow, kc*32 + quad*8, ah, al);
        a4 = mfma3(ah, al, B4h[kc], B4l[kc], a4);
      }
    }
    #pragma unroll
    for (int r = 0; r < 4; ++r){
      int n = base + m*16 + quad*4 + r;
      if (n < N) out[(size_t)n*64 + nb*16 + nl] = a4[r];
    }
  }
}

extern "C" void kernel_launch(void* const* d_in, const int* in_sizes, int n_in,
                              void* d_out, int out_size, void* d_ws, size_t ws_size,
                              hipStream_t stream) {
  const float* nf  = (const float*)d_in[0];
  const float* ef  = (const float*)d_in[1];
  const int*   src = (const int*)d_in[2];
  const int*   dst = (const int*)d_in[3];

  const int N = in_sizes[0] / 64;
  const int E = in_sizes[2];

  float* nf1 = (float*)d_ws;               // [N,32] segment-sum
  float* nf2 = nf1 + (size_t)N * 32;       // [N,32] segment-max
  float* P   = nf2 + (size_t)N * 32;       // [N,128] node-precomputed L1 partials

  size_t need = (size_t)N * 64 * 4 + (size_t)N * 128 * 4;
  bool useP = (ws_size >= need);

  static bool attr_set = false;
  if (!attr_set){
    hipFuncSetAttribute((const void*)edge_mfma,
                        hipFuncAttributeMaxDynamicSharedMemorySize, LDS_BYTES);
    hipFuncSetAttribute((const void*)edge_mfma_p,
                        hipFuncAttributeMaxDynamicSharedMemorySize, P_LDS_BYTES);
    attr_set = true;
  }

  init_ws<<<2048, 256, 0, stream>>>(nf1, nf2, N * 32);

  if (useP){
    node_pre<<<1024, 256, 0, stream>>>(nf, (const float*)d_in[4], P, N);
    edge_mfma_p<<<2048, 256, P_LDS_BYTES, stream>>>(
        P, ef, src, dst,
        (const float*)d_in[4],  (const float*)d_in[5],  (const float*)d_in[6],  (const float*)d_in[7],
        (const float*)d_in[8],  (const float*)d_in[9],  (const float*)d_in[10], (const float*)d_in[11],
        nf1, nf2, E);
  } else {
    edge_mfma<<<2048, 256, LDS_BYTES, stream>>>(
        nf, ef, src, dst,
        (const float*)d_in[4],  (const float*)d_in[5],  (const float*)d_in[6],  (const float*)d_in[7],
        (const float*)d_in[8],  (const float*)d_in[9],  (const float*)d_in[10], (const float*)d_in[11],
        nf1, nf2, E);
  }

  node_mfma<<<512, 512, 0, stream>>>(
      nf, nf1, nf2,
      (const float*)d_in[12], (const float*)d_in[13], (const float*)d_in[14], (const float*)d_in[15],
      (const float*)d_in[16], (const float*)d_in[17], (const float*)d_in[18], (const float*)d_in[19],
      (float*)d_out, N);
}

// Round 7
// 1053.136 us; speedup vs baseline: 1.4114x; 1.0690x over previous
//
#include <hip/hip_runtime.h>

typedef unsigned int u32;
typedef __attribute__((ext_vector_type(8))) short short8;
typedef __attribute__((ext_vector_type(4))) short short4v;
typedef __attribute__((ext_vector_type(4))) float f32x4;

__device__ __forceinline__ float lrelu(float x){ return x > 0.f ? x : 0.2f*x; }

// lgkm-only barrier: make LDS visible across waves WITHOUT draining vmcnt
// (atomics/loads keep flying; __syncthreads would force vmcnt(0) = full atomic drain)
#define BAR_LGKM() do { asm volatile("s_waitcnt lgkmcnt(0)" ::: "memory"); \
                        __builtin_amdgcn_s_barrier(); } while(0)

// float atomic max via sign-split (dest init -inf)
__device__ __forceinline__ void atomicMaxF(float* a, float v){
  if (__float_as_int(v) >= 0) atomicMax((int*)a, __float_as_int(v));
  else                        atomicMin((u32*)a, __float_as_uint(v));
}

__global__ void init_ws(float* __restrict__ nf1, float* __restrict__ nf2, int n32){
  int i = blockIdx.x*blockDim.x + threadIdx.x;
  int st = gridDim.x*blockDim.x;
  for (; i < n32; i += st){ nf1[i] = 0.f; nf2[i] = -__builtin_inff(); }
}

// RNE split: x = bf16(hi) + bf16(lo) + O(2^-18 x).
struct HL { short hi, lo; };
__device__ __forceinline__ HL split1(float x){
  u32 u = __float_as_uint(x);
  u32 r = u + 0x7FFFu + ((u >> 16) & 1u);
  float l = x - __uint_as_float(r & 0xFFFF0000u);
  HL o; o.hi = (short)(r >> 16); o.lo = (short)(__float_as_uint(l) >> 16);
  return o;
}

// one-time gather of a B fragment (W row-major [K][Nout], f32) with zero-fill OOB
__device__ __forceinline__ void gatherB(const float* __restrict__ W, int K, int Nout,
                                        int kbase, int n, short8& hi, short8& lo){
  #pragma unroll
  for (int j = 0; j < 8; ++j){
    int k = kbase + j;
    float w = (k < K && n < Nout) ? W[(size_t)k * Nout + n] : 0.f;
    HL s = split1(w); hi[j] = s.hi; lo[j] = s.lo;
  }
}

// 3-product accurate bf16 MFMA: D += Ah*Bh + Al*Bh + Ah*Bl
__device__ __forceinline__ f32x4 mfma3(short8 ah, short8 al, short8 bh, short8 bl, f32x4 c){
  c = __builtin_amdgcn_mfma_f32_16x16x32_bf16(ah, bh, c, 0, 0, 0);
  c = __builtin_amdgcn_mfma_f32_16x16x32_bf16(al, bh, c, 0, 0, 0);
  c = __builtin_amdgcn_mfma_f32_16x16x32_bf16(ah, bl, c, 0, 0, 0);
  return c;
}

// pre-split stores: split once at producer, consumers ds_read_b128 hi/lo planes directly
__device__ __forceinline__ void sstore1(short* hp, short* lp, int idx, float x){
  HL s = split1(x); hp[idx] = s.hi; lp[idx] = s.lo;
}
__device__ __forceinline__ void sstore4(short* hp, short* lp, int idx, f32x4 v){
  short4v h, l;
  #pragma unroll
  for (int j = 0; j < 4; ++j){ HL s = split1(v[j]); h[j] = s.hi; l[j] = s.lo; }
  *(short4v*)(hp + idx) = h;
  *(short4v*)(lp + idx) = l;
}

// ---------------- node_pre: P[n] = [ nf[n]·Wm1[0:64] | nf[n]·Wm1[64:128] ] (f32) ----------
__global__ __launch_bounds__(256, 2) void node_pre(
    const float* __restrict__ nf, const float* __restrict__ Wm1,
    float* __restrict__ P, int N)
{
  __shared__ short Xnh[32*72];
  __shared__ short Xnl[32*72];

  const int lane = threadIdx.x & 63, wv = threadIdx.x >> 6;
  const int nl = lane & 15, quad = lane >> 4;
  const int nb = wv;
  const int slot = wv*4 + quad;

  short8 Bah[2], Bal[2], Bbh[2], Bbl[2];
  #pragma unroll
  for (int kc = 0; kc < 2; ++kc){
    gatherB(Wm1, 144, 64, kc*32 + quad*8,      nb*16 + nl, Bah[kc], Bal[kc]);
    gatherB(Wm1, 144, 64, 64 + kc*32 + quad*8, nb*16 + nl, Bbh[kc], Bbl[kc]);
  }

  const int ntiles = (N + 31) >> 5;
  for (int t = blockIdx.x; t < ntiles; t += gridDim.x){
    const int base = t << 5;
    #pragma unroll
    for (int r2 = 0; r2 < 2; ++r2){
      int row = slot*2 + r2;
      int n = base + row;
      int nc = n < N ? n : 0;
      f32x4 v = *(const f32x4*)(nf + (size_t)nc*64 + nl*4);
      sstore4(Xnh, Xnl, row*72 + nl*4, v);
    }
    __syncthreads();

    f32x4 aa[2] = {{0,0,0,0},{0,0,0,0}};
    f32x4 ab[2] = {{0,0,0,0},{0,0,0,0}};
    #pragma unroll
    for (int kc = 0; kc < 2; ++kc)
      #pragma unroll
      for (int mb = 0; mb < 2; ++mb){
        int ro = (mb*16 + nl)*72 + kc*32 + quad*8;
        short8 ah = *(const short8*)(Xnh + ro);
        short8 al = *(const short8*)(Xnl + ro);
        aa[mb] = mfma3(ah, al, Bah[kc], Bal[kc], aa[mb]);
        ab[mb] = mfma3(ah, al, Bbh[kc], Bbl[kc], ab[mb]);
      }
    #pragma unroll
    for (int mb = 0; mb < 2; ++mb)
      #pragma unroll
      for (int r = 0; r < 4; ++r){
        int n = base + mb*16 + quad*4 + r;
        if (n < N){
          P[(size_t)n*128 +      nb*16 + nl] = aa[mb][r];
          P[(size_t)n*128 + 64 + nb*16 + nl] = ab[mb][r];
        }
      }
    __syncthreads();
  }
}

// ---- P-path edge kernel LDS geometry (shorts), parity-buffered Xe/S/H1/dstI ----
#define PXES  40            // ef planes stride: 16 real cols + 16 zero-pad
#define PSS   68            // S stride in f32
#define PH1S  72
#define PH2S  136
#define POFF_XEH  0         // Xeh[2]: q*1280
#define POFF_XEL  2560      // Xel[2]: q*1280
#define POFF_S    5120      // f32 S[2][32*68] = 2*2176 floats = 8704 shorts
#define POFF_H1H  13824     // H1h[2]: q*2304
#define POFF_H1L  18432     // H1l[2]: q*2304
#define POFF_H2H  23040     // 4352
#define POFF_H2L  27392     // 4352
#define POFF_DST  31744     // int dstI[2][32]
#define P_LDS_SHORTS 31872
#define P_LDS_BYTES  (P_LDS_SHORTS*2)   // 63744 B -> 2 blocks/CU (reg cap: 8 waves/CU)

// -------- P-path edge kernel: 32 edges/tile, 4 waves, 3 lgkm-only barriers/tile --------
// h1 = lrelu( S + ef·W1c + b1 ), S = P[src][0:64] + P[dst][64:128].
// Stage for tile t+1 runs UNDER L2/L3 (between bars B and C); atomics never drained in-loop.
// Race audit (all via lgkm barriers B/C/D):
//   Xe/S/dstI[q]: written (stage, before C of iter t) -> read (L1/L4 of iter t+1, after D) OK
//                 prev reader was iter t-1 (L1 before its bar B; bars D(t-1),B(t) intervene) OK
//   H1[q]: L1(t) writes before B(t); L2(t) reads before C(t); L3(t) rewrites before D(t);
//          L4(t) reads after D(t). Next writer is L1(t+2) (parity) - separated by B(t+1). OK
//   H2: L2(t) writes before C(t); L3(t) reads before D(t); next writer L2(t+1) after B(t+1). OK
// NOTE: ~250 unified regs/wave -> hard cap 8 waves/CU; never tighten launch_bounds
// (rounds 1&3: forcing more waves spills -> FETCH explodes).
__global__ __launch_bounds__(256, 2) void edge_mfma_p(
    const float* __restrict__ P, const float* __restrict__ ef,
    const int* __restrict__ src, const int* __restrict__ dst,
    const float* __restrict__ Wm1, const float* __restrict__ bm1,
    const float* __restrict__ Wm2, const float* __restrict__ bm2,
    const float* __restrict__ Wm3, const float* __restrict__ bm3,
    const float* __restrict__ Wm4, const float* __restrict__ bm4,
    float* __restrict__ nf1, float* __restrict__ nf2, int E)
{
  extern __shared__ short smem[];
  float* Sbase = (float*)(smem + POFF_S);
  int*   dstI  = (int*)(smem + POFF_DST);

  // one-time zero of Xe planes (pads 16..31 must stay 0; never aliased)
  {
    float* z = (float*)smem;
    for (int i = threadIdx.x; i < POFF_S/2; i += blockDim.x) z[i] = 0.f;
  }

  const int lane = threadIdx.x & 63, wv = threadIdx.x >> 6;
  const int nl = lane & 15, quad = lane >> 4;
  const int nb1 = wv;
  const int slot = wv*4 + quad;

  // ---- loop-invariant B fragments ----
  short8 B1ch, B1cl;
  gatherB(Wm1, 144, 64, 128 + quad*8, nb1*16 + nl, B1ch, B1cl);
  short8 B2h[2][2], B2l[2][2];
  #pragma unroll
  for (int i = 0; i < 2; ++i)
    #pragma unroll
    for (int kc = 0; kc < 2; ++kc) gatherB(Wm2, 64, 128, kc*32 + quad*8, (nb1 + i*4)*16 + nl, B2h[i][kc], B2l[i][kc]);
  short8 B3h[4], B3l[4];
  #pragma unroll
  for (int kc = 0; kc < 4; ++kc) gatherB(Wm3, 128, 64,  kc*32 + quad*8, nb1*16 + nl, B3h[kc], B3l[kc]);
  short8 B4h[2], B4l[2];
  #pragma unroll
  for (int kc = 0; kc < 2; ++kc) gatherB(Wm4, 64, 65, kc*32 + quad*8, nb1*16 + nl, B4h[kc], B4l[kc]);
  const int gcol = (nl < 8) ? 0 : 64;
  short8 Bgh[2], Bgl[2];
  #pragma unroll
  for (int kc = 0; kc < 2; ++kc) gatherB(Wm4, 64, 65, kc*32 + quad*8, gcol, Bgh[kc], Bgl[kc]);

  const float bi1  = bm1[nb1*16 + nl];
  const float bi2a = bm2[nb1*16 + nl], bi2b = bm2[(nb1+4)*16 + nl];
  const float bi3  = bm3[nb1*16 + nl];
  const float bi4a = bm4[nb1*16 + nl];
  const float big  = bm4[gcol];

  const int ntiles = (E + 31) >> 5;
  const int stride = gridDim.x;

  // ---- stage helper (macro to keep addressing in registers) ----
  #define STAGE(TT, Q)                                                              \
    do {                                                                            \
      short* xh = smem + POFF_XEH + (Q)*1280;                                       \
      short* xl = smem + POFF_XEL + (Q)*1280;                                       \
      float* sb = Sbase + (Q)*2176;                                                 \
      _Pragma("unroll")                                                             \
      for (int r2 = 0; r2 < 2; ++r2){                                               \
        int row = slot*2 + r2;                                                      \
        int e = ((TT) << 5) + row;                                                  \
        int ec = e < E ? e : 0;                                                     \
        int s = src[ec], d = dst[ec];                                               \
        f32x4 a = *(const f32x4*)(P + (size_t)s*128 +      nl*4);                   \
        f32x4 b = *(const f32x4*)(P + (size_t)d*128 + 64 + nl*4);                   \
        *(f32x4*)(sb + row*PSS + nl*4) = a + b;                                     \
        if (nl < 4){                                                                \
          f32x4 v2 = *(const f32x4*)(ef + (size_t)ec*16 + nl*4);                    \
          sstore4(xh, xl, row*PXES + nl*4, v2);                                     \
        }                                                                           \
        if (nl == 5) dstI[(Q)*32 + row] = (e < E) ? d : -1;                         \
      }                                                                             \
    } while(0)

  // prologue: zeros + first stage, then one full barrier (waves may still be in gatherB)
  __syncthreads();
  if (blockIdx.x < ntiles) STAGE(blockIdx.x, 0);
  BAR_LGKM();

  int pp = 0;
  for (int t = blockIdx.x; t < ntiles; t += stride, pp ^= 1){
    short* xh  = smem + POFF_XEH + pp*1280;
    short* xl  = smem + POFF_XEL + pp*1280;
    float* sb  = Sbase + pp*2176;
    short* h1h = smem + POFF_H1H + pp*2304;
    short* h1l = smem + POFF_H1L + pp*2304;
    short* H2h = smem + POFF_H2H;
    short* H2l = smem + POFF_H2L;

    // ---- L1: K=32 ef-only + S epilogue add -> H1[pp] ----
    {
      f32x4 a1[2] = {{bi1,bi1,bi1,bi1},{bi1,bi1,bi1,bi1}};
      #pragma unroll
      for (int mb = 0; mb < 2; ++mb){
        int ro = (mb*16 + nl)*PXES + quad*8;
        short8 ah = *(const short8*)(xh + ro);
        short8 al = *(const short8*)(xl + ro);
        a1[mb] = mfma3(ah, al, B1ch, B1cl, a1[mb]);
      }
      #pragma unroll
      for (int mb = 0; mb < 2; ++mb)
        #pragma unroll
        for (int r = 0; r < 4; ++r){
          int row = mb*16 + quad*4 + r;
          float sv = sb[row*PSS + nb1*16 + nl];
          sstore1(h1h, h1l, row*PH1S + nb1*16 + nl, lrelu(a1[mb][r] + sv));
        }
    }
    BAR_LGKM();   // B: H1[pp] visible

    // ---- stage tile t+stride into parity pp^1 (latency hides under L2/L3) ----
    {
      int tn = t + stride;
      if (tn < ntiles) STAGE(tn, pp^1);
    }

    // ---- L2: K=64, dual n-block, H1[pp] -> H2 ----
    {
      f32x4 a2a[2] = {{bi2a,bi2a,bi2a,bi2a},{bi2a,bi2a,bi2a,bi2a}};
      f32x4 a2b[2] = {{bi2b,bi2b,bi2b,bi2b},{bi2b,bi2b,bi2b,bi2b}};
      #pragma unroll
      for (int kc = 0; kc < 2; ++kc)
        #pragma unroll
        for (int mb = 0; mb < 2; ++mb){
          int ro = (mb*16 + nl)*PH1S + kc*32 + quad*8;
          short8 ah = *(const short8*)(h1h + ro);
          short8 al = *(const short8*)(h1l + ro);
          a2a[mb] = mfma3(ah, al, B2h[0][kc], B2l[0][kc], a2a[mb]);
          a2b[mb] = mfma3(ah, al, B2h[1][kc], B2l[1][kc], a2b[mb]);
        }
      #pragma unroll
      for (int mb = 0; mb < 2; ++mb)
        #pragma unroll
        for (int r = 0; r < 4; ++r){
          int row = mb*16 + quad*4 + r;
          sstore1(H2h, H2l, row*PH2S + nb1*16 + nl,     lrelu(a2a[mb][r]));
          sstore1(H2h, H2l, row*PH2S + (nb1+4)*16 + nl, lrelu(a2b[mb][r]));
        }
    }
    BAR_LGKM();   // C: H2 + staged Xe/S/dstI[pp^1] visible

    // ---- L3: K=128, H2 -> H1[pp] (L2 reads of H1 done at C) ----
    {
      f32x4 a3[2] = {{bi3,bi3,bi3,bi3},{bi3,bi3,bi3,bi3}};
      #pragma unroll
      for (int kc = 0; kc < 4; ++kc)
        #pragma unroll
        for (int mb = 0; mb < 2; ++mb){
          int ro = (mb*16 + nl)*PH2S + kc*32 + quad*8;
          short8 ah = *(const short8*)(H2h + ro);
          short8 al = *(const short8*)(H2l + ro);
          a3[mb] = mfma3(ah, al, B3h[kc], B3l[kc], a3[mb]);
        }
      #pragma unroll
      for (int mb = 0; mb < 2; ++mb)
        #pragma unroll
        for (int r = 0; r < 4; ++r)
          sstore1(h1h, h1l, (mb*16 + quad*4 + r)*PH1S + nb1*16 + nl, lrelu(a3[mb][r]));
    }
    BAR_LGKM();   // D: H1[pp] rewritten visible

    // ---- L4 + scatter (fire-and-forget atomics; never drained in-loop) ----
    {
      f32x4 a4[2] = {{bi4a,bi4a,bi4a,bi4a},{bi4a,bi4a,bi4a,bi4a}};
      f32x4 ag[2] = {{big,big,big,big},{big,big,big,big}};
      #pragma unroll
      for (int kc = 0; kc < 2; ++kc)
        #pragma unroll
        for (int mb = 0; mb < 2; ++mb){
          int ro = (mb*16 + nl)*PH1S + kc*32 + quad*8;
          short8 ah = *(const short8*)(h1h + ro);
          short8 al = *(const short8*)(h1l + ro);
          a4[mb] = mfma3(ah, al, B4h[kc], B4l[kc], a4[mb]);
          ag[mb] = mfma3(ah, al, Bgh[kc], Bgl[kc], ag[mb]);
        }
      const int n = nb1*16 + nl;
      #pragma unroll
      for (int mb = 0; mb < 2; ++mb)
        #pragma unroll
        for (int r = 0; r < 4; ++r){
          int row = mb*16 + quad*4 + r;
          float glog = __shfl(ag[mb][r], lane & 0x30);
          float g = 1.f/(1.f + __expf(-glog));
          int d = dstI[pp*32 + row];
          if (d >= 0){
            float v = a4[mb][r] * g;
            if (n >= 1 && n <= 32)  atomicAdd(nf1 + (size_t)d*32 + (n-1), v);
            else if (n >= 33)       atomicMaxF(nf2 + (size_t)d*32 + (n-33), v);
            if (nb1 == 0 && nl == 8)
              atomicMaxF(nf2 + (size_t)d*32 + 31, ag[mb][r] * g);
          }
        }
    }
    // no tail barrier: next L1 reads Xe/S[pp^1] (visible since C) and writes H1[pp^1] (parity)
  }
  #undef STAGE
}

// ---------------- fallback edge kernel (round-5, proven) -------------------------
#define XS   168
#define H1S  72
#define H2S  136
#define OFF_XL   5376
#define OFF_H2H  0
#define OFF_H2L  4352
#define OFF_H1H  10752
#define OFF_H1L  13056
#define OFF_DST  15360
#define LDS_SHORTS 15488
#define LDS_BYTES  (LDS_SHORTS*2)

__global__ __launch_bounds__(256, 2) void edge_mfma(
    const float* __restrict__ nf, const float* __restrict__ ef,
    const int* __restrict__ src, const int* __restrict__ dst,
    const float* __restrict__ Wm1, const float* __restrict__ bm1,
    const float* __restrict__ Wm2, const float* __restrict__ bm2,
    const float* __restrict__ Wm3, const float* __restrict__ bm3,
    const float* __restrict__ Wm4, const float* __restrict__ bm4,
    float* __restrict__ nf1, float* __restrict__ nf2, int E)
{
  extern __shared__ short smem[];
  short* Xh  = smem;
  short* Xl  = smem + OFF_XL;
  short* H2h = smem + OFF_H2H;
  short* H2l = smem + OFF_H2L;
  short* H1h = smem + OFF_H1H;
  short* H1l = smem + OFF_H1L;
  int*  dstI = (int*)(smem + OFF_DST);

  const int lane = threadIdx.x & 63, wv = threadIdx.x >> 6;
  const int nl = lane & 15, quad = lane >> 4;
  const int nb1 = wv;
  const int slot = wv*4 + quad;

  short8 B1h[5], B1l[5];
  #pragma unroll
  for (int kc = 0; kc < 5; ++kc) gatherB(Wm1, 144, 64,  kc*32 + quad*8, nb1*16 + nl, B1h[kc], B1l[kc]);
  short8 B2h[2][2], B2l[2][2];
  #pragma unroll
  for (int i = 0; i < 2; ++i)
    #pragma unroll
    for (int kc = 0; kc < 2; ++kc) gatherB(Wm2, 64, 128, kc*32 + quad*8, (nb1 + i*4)*16 + nl, B2h[i][kc], B2l[i][kc]);
  short8 B3h[4], B3l[4];
  #pragma unroll
  for (int kc = 0; kc < 4; ++kc) gatherB(Wm3, 128, 64,  kc*32 + quad*8, nb1*16 + nl, B3h[kc], B3l[kc]);
  short8 B4h[2], B4l[2];
  #pragma unroll
  for (int kc = 0; kc < 2; ++kc) gatherB(Wm4, 64, 65, kc*32 + quad*8, nb1*16 + nl, B4h[kc], B4l[kc]);
  const int gcol = (nl < 8) ? 0 : 64;
  short8 Bgh[2], Bgl[2];
  #pragma unroll
  for (int kc = 0; kc < 2; ++kc) gatherB(Wm4, 64, 65, kc*32 + quad*8, gcol, Bgh[kc], Bgl[kc]);

  const float bi1  = bm1[nb1*16 + nl];
  const float bi2a = bm2[nb1*16 + nl], bi2b = bm2[(nb1+4)*16 + nl];
  const float bi3  = bm3[nb1*16 + nl];
  const float bi4a = bm4[nb1*16 + nl];
  const float big  = bm4[gcol];

  const int ntiles = (E + 31) >> 5;
  int pp = 0;
  for (int t = blockIdx.x; t < ntiles; t += gridDim.x, pp ^= 1){
    #pragma unroll
    for (int r2 = 0; r2 < 2; ++r2){
      int row = slot*2 + r2;
      int e = (t << 5) + row;
      int ec = e < E ? e : 0;
      int s = src[ec], d = dst[ec];
      f32x4 v0 = *(const f32x4*)(nf + (size_t)s*64 + nl*4);
      f32x4 v1 = *(const f32x4*)(nf + (size_t)d*64 + nl*4);
      sstore4(Xh, Xl, row*XS + nl*4,      v0);
      sstore4(Xh, Xl, row*XS + 64 + nl*4, v1);
      if (nl < 4){
        f32x4 v2 = *(const f32x4*)(ef + (size_t)ec*16 + nl*4);
        sstore4(Xh, Xl, row*XS + 128 + nl*4, v2);
      } else if (nl < 8){
        short4v z = {0,0,0,0};
        *(short4v*)(Xh + row*XS + 144 + (nl-4)*4) = z;
        *(short4v*)(Xl + row*XS + 144 + (nl-4)*4) = z;
      }
      if (nl == 5) dstI[pp*32 + row] = (e < E) ? d : -1;
    }
    __syncthreads();

    {
      f32x4 a1[2] = {{bi1,bi1,bi1,bi1},{bi1,bi1,bi1,bi1}};
      #pragma unroll
      for (int kc = 0; kc < 5; ++kc)
        #pragma unroll
        for (int mb = 0; mb < 2; ++mb){
          int ro = (mb*16 + nl)*XS + kc*32 + quad*8;
          short8 ah = *(const short8*)(Xh + ro);
          short8 al = *(const short8*)(Xl + ro);
          a1[mb] = mfma3(ah, al, B1h[kc], B1l[kc], a1[mb]);
        }
      #pragma unroll
      for (int mb = 0; mb < 2; ++mb)
        #pragma unroll
        for (int r = 0; r < 4; ++r)
          sstore1(H1h, H1l, (mb*16 + quad*4 + r)*H1S + nb1*16 + nl, lrelu(a1[mb][r]));
    }
    __syncthreads();

    {
      f32x4 a2a[2] = {{bi2a,bi2a,bi2a,bi2a},{bi2a,bi2a,bi2a,bi2a}};
      f32x4 a2b[2] = {{bi2b,bi2b,bi2b,bi2b},{bi2b,bi2b,bi2b,bi2b}};
      #pragma unroll
      for (int kc = 0; kc < 2; ++kc)
        #pragma unroll
        for (int mb = 0; mb < 2; ++mb){
          int ro = (mb*16 + nl)*H1S + kc*32 + quad*8;
          short8 ah = *(const short8*)(H1h + ro);
          short8 al = *(const short8*)(H1l + ro);
          a2a[mb] = mfma3(ah, al, B2h[0][kc], B2l[0][kc], a2a[mb]);
          a2b[mb] = mfma3(ah, al, B2h[1][kc], B2l[1][kc], a2b[mb]);
        }
      #pragma unroll
      for (int mb = 0; mb < 2; ++mb)
        #pragma unroll
        for (int r = 0; r < 4; ++r){
          int row = mb*16 + quad*4 + r;
          sstore1(H2h, H2l, row*H2S + nb1*16 + nl,     lrelu(a2a[mb][r]));
          sstore1(H2h, H2l, row*H2S + (nb1+4)*16 + nl, lrelu(a2b[mb][r]));
        }
    }
    __syncthreads();

    {
      f32x4 a3[2] = {{bi3,bi3,bi3,bi3},{bi3,bi3,bi3,bi3}};
      #pragma unroll
      for (int kc = 0; kc < 4; ++kc)
        #pragma unroll
        for (int mb = 0; mb < 2; ++mb){
          int ro = (mb*16 + nl)*H2S + kc*32 + quad*8;
          short8 ah = *(const short8*)(H2h + ro);
          short8 al = *(const short8*)(H2l + ro);
          a3[mb] = mfma3(ah, al, B3h[kc], B3l[kc], a3[mb]);
        }
      #pragma unroll
      for (int mb = 0; mb < 2; ++mb)
        #pragma unroll
        for (int r = 0; r < 4; ++r)
          sstore1(H1h, H1l, (mb*16 + quad*4 + r)*H1S + nb1*16 + nl, lrelu(a3[mb][r]));
    }
    __syncthreads();

    {
      f32x4 a4[2] = {{bi4a,bi4a,bi4a,bi4a},{bi4a,bi4a,bi4a,bi4a}};
      f32x4 ag[2] = {{big,big,big,big},{big,big,big,big}};
      #pragma unroll
      for (int kc = 0; kc < 2; ++kc)
        #pragma unroll
        for (int mb = 0; mb < 2; ++mb){
          int ro = (mb*16 + nl)*H1S + kc*32 + quad*8;
          short8 ah = *(const short8*)(H1h + ro);
          short8 al = *(const short8*)(H1l + ro);
          a4[mb] = mfma3(ah, al, B4h[kc], B4l[kc], a4[mb]);
          ag[mb] = mfma3(ah, al, Bgh[kc], Bgl[kc], ag[mb]);
        }
      const int n = nb1*16 + nl;
      #pragma unroll
      for (int mb = 0; mb < 2; ++mb)
        #pragma unroll
        for (int r = 0; r < 4; ++r){
          int row = mb*16 + quad*4 + r;
          float glog = __shfl(ag[mb][r], lane & 0x30);
          float g = 1.f/(1.f + __expf(-glog));
          int d = dstI[pp*32 + row];
          if (d >= 0){
            float v = a4[mb][r] * g;
            if (n >= 1 && n <= 32)  atomicAdd(nf1 + (size_t)d*32 + (n-1), v);
            else if (n >= 33)       atomicMaxF(nf2 + (size_t)d*32 + (n-33), v);
            if (nb1 == 0 && nl == 8)
              atomicMaxF(nf2 + (size_t)d*32 + 31, ag[mb][r] * g);
          }
        }
    }
  }
}

__device__ void zero_f(float* p, int n){
  for (int i = threadIdx.x; i < n; i += blockDim.x) p[i] = 0.f;
}

#define B1S 68
#define C0S 132

__device__ __forceinline__ void splitA(const float* arow, int k0, short8& hi, short8& lo){
  f32x4 x0 = *(const f32x4*)(arow + k0);
  f32x4 x1 = *(const f32x4*)(arow + k0 + 4);
  #pragma unroll
  for (int j = 0; j < 4; ++j){
    HL a = split1(x0[j]); hi[j]   = a.hi; lo[j]   = a.lo;
    HL b = split1(x1[j]); hi[4+j] = b.hi; lo[4+j] = b.lo;
  }
}

// -------- node kernel: 32 nodes per block-tile, 8 waves (unchanged) --------
__global__ __launch_bounds__(512, 2) void node_mfma(
    const float* __restrict__ nf,
    const float* __restrict__ nf1, const float* __restrict__ nf2,
    const float* __restrict__ Wr1, const float* __restrict__ br1,
    const float* __restrict__ Wr2, const float* __restrict__ br2,
    const float* __restrict__ Wr3, const float* __restrict__ br3,
    const float* __restrict__ Wr4, const float* __restrict__ br4,
    float* __restrict__ out, int N)
{
  __shared__ float buf0[32*C0S];
  __shared__ float buf1[32*B1S];

  zero_f(buf0, 32*C0S);
  zero_f(buf1, 32*B1S);

  const int lane = threadIdx.x & 63, wv = threadIdx.x >> 6;
  const int nl = lane & 15, quad = lane >> 4;
  const int m = wv >> 2, nb = wv & 3;

  short8 B1h[4], B1l[4];
  #pragma unroll
  for (int kc = 0; kc < 4; ++kc) gatherB(Wr1, 128, 64,  kc*32 + quad*8, nb*16 + nl, B1h[kc], B1l[kc]);
  short8 B2h[2][2], B2l[2][2];
  #pragma unroll
  for (int i = 0; i < 2; ++i)
    #pragma unroll
    for (int kc = 0; kc < 2; ++kc) gatherB(Wr2, 64, 128, kc*32 + quad*8, (nb + i*4)*16 + nl, B2h[i][kc], B2l[i][kc]);
  short8 B3h[4], B3l[4];
  #pragma unroll
  for (int kc = 0; kc < 4; ++kc) gatherB(Wr3, 128, 64,  kc*32 + quad*8, nb*16 + nl, B3h[kc], B3l[kc]);
  short8 B4h[2], B4l[2];
  #pragma unroll
  for (int kc = 0; kc < 2; ++kc) gatherB(Wr4, 64, 64,   kc*32 + quad*8, nb*16 + nl, B4h[kc], B4l[kc]);

  const float bi1  = br1[nb*16 + nl];
  const float bi2a = br2[nb*16 + nl], bi2b = br2[(nb+4)*16 + nl];
  const float bi3  = br3[nb*16 + nl];
  const float bi4  = br4[nb*16 + nl];
  __syncthreads();

  const int ntiles = (N + 31) >> 5;
  for (int t = blockIdx.x; t < ntiles; t += gridDim.x){
    const int base = t << 5;
    {
      int row = wv*4 + quad;
      int n = base + row;
      int nc = n < N ? n : 0;
      *(f32x4*)(buf0 + row*C0S + nl*4) = *(const f32x4*)(nf + (size_t)nc*64 + nl*4);
      if (nl < 8){
        *(f32x4*)(buf0 + row*C0S + 64 + nl*4) = *(const f32x4*)(nf1 + (size_t)nc*32 + nl*4);
      } else {
        f32x4 v = *(const f32x4*)(nf2 + (size_t)nc*32 + (nl-8)*4);
        #pragma unroll
        for (int j = 0; j < 4; ++j) if (!(v[j] >= -3.0e38f)) v[j] = 0.f;
        *(f32x4*)(buf0 + row*C0S + 96 + (nl-8)*4) = v;
      }
    }
    __syncthreads();

    f32x4 a1 = {bi1, bi1, bi1, bi1};
    {
      const float* arow = buf0 + (m*16 + nl)*C0S;
      #pragma unroll
      for (int kc = 0; kc < 4; ++kc){
        short8 ah, al; splitA(arow, kc*32 + quad*8, ah, al);
        a1 = mfma3(ah, al, B1h[kc], B1l[kc], a1);
      }
    }
    #pragma unroll
    for (int r = 0; r < 4; ++r)
      buf1[(m*16 + quad*4 + r)*B1S + nb*16 + nl] = lrelu(a1[r]);
    __syncthreads();

    f32x4 a2a = {bi2a, bi2a, bi2a, bi2a}, a2b = {bi2b, bi2b, bi2b, bi2b};
    {
      const float* arow = buf1 + (m*16 + nl)*B1S;
      #pragma unroll
      for (int kc = 0; kc < 2; ++kc){
        short8 ah, al; splitA(arow, kc*32 + quad*8, ah, al);
        a2a = mfma3(ah, al, B2h[0][kc], B2l[0][kc], a2a);
        a2b = mfma3(ah, al, B2h[1][kc], B2l[1][kc], a2b);
      }
    }
    #pragma unroll
    for (int r = 0; r < 4; ++r){
      buf0[(m*16 + quad*4 + r)*C0S + nb*16 + nl]     = lrelu(a2a[r]);
      buf0[(m*16 + quad*4 + r)*C0S + (nb+4)*16 + nl] = lrelu(a2b[r]);
    }
    __syncthreads();

    f32x4 a3 = {bi3, bi3, bi3, bi3};
    {
      const float* arow = buf0 + (m*16 + nl)*C0S;
      #pragma unroll
      for (int kc = 0; kc < 4; ++kc){
        short8 ah, al; splitA(arow, kc*32 + quad*8, ah, al);
        a3 = mfma3(ah, al, B3h[kc], B3l[kc], a3);
      }
    }
    #pragma unroll
    for (int r = 0; r < 4; ++r)
      buf1[(m*16 + quad*4 + r)*B1S + nb*16 + nl] = lrelu(a3[r]);
    __syncthreads();

    f32x4 a4 = {bi4, bi4, bi4, bi4};
    {
      const float* arow = buf1 + (m*16 + nl)*B1S;
      #pragma unroll
      for (int kc = 0; kc < 2; ++kc){
        short8 ah, al; splitA(arow, kc*32 + quad*8, ah, al);
        a4 = mfma3(ah, al, B4h[kc], B4l[kc], a4);
      }
    }
    #pragma unroll
    for (int r = 0; r < 4; ++r){
      int n = base + m*16 + quad*4 + r;
      if (n < N) out[(size_t)n*64 + nb*16 + nl] = a4[r];
    }
  }
}

extern "C" void kernel_launch(void* const* d_in, const int* in_sizes, int n_in,
                              void* d_out, int out_size, void* d_ws, size_t ws_size,
                              hipStream_t stream) {
  const float* nf  = (const float*)d_in[0];
  const float* ef  = (const float*)d_in[1];
  const int*   src = (const int*)d_in[2];
  const int*   dst = (const int*)d_in[3];

  const int N = in_sizes[0] / 64;
  const int E = in_sizes[2];

  float* nf1 = (float*)d_ws;               // [N,32] segment-sum
  float* nf2 = nf1 + (size_t)N * 32;       // [N,32] segment-max
  float* P   = nf2 + (size_t)N * 32;       // [N,128] node-precomputed L1 partials

  size_t need = (size_t)N * 64 * 4 + (size_t)N * 128 * 4;
  bool useP = (ws_size >= need);

  static bool attr_set = false;
  if (!attr_set){
    hipFuncSetAttribute((const void*)edge_mfma,
                        hipFuncAttributeMaxDynamicSharedMemorySize, LDS_BYTES);
    hipFuncSetAttribute((const void*)edge_mfma_p,
                        hipFuncAttributeMaxDynamicSharedMemorySize, P_LDS_BYTES);
    attr_set = true;
  }

  init_ws<<<2048, 256, 0, stream>>>(nf1, nf2, N * 32);

  if (useP){
    node_pre<<<1024, 256, 0, stream>>>(nf, (const float*)d_in[4], P, N);
    edge_mfma_p<<<2048, 256, P_LDS_BYTES, stream>>>(
        P, ef, src, dst,
        (const float*)d_in[4],  (const float*)d_in[5],  (const float*)d_in[6],  (const float*)d_in[7],
        (const float*)d_in[8],  (const float*)d_in[9],  (const float*)d_in[10], (const float*)d_in[11],
        nf1, nf2, E);
  } else {
    edge_mfma<<<2048, 256, LDS_BYTES, stream>>>(
        nf, ef, src, dst,
        (const float*)d_in[4],  (const float*)d_in[5],  (const float*)d_in[6],  (const float*)d_in[7],
        (const float*)d_in[8],  (const float*)d_in[9],  (const float*)d_in[10], (const float*)d_in[11],
        nf1, nf2, E);
  }

  node_mfma<<<512, 512, 0, stream>>>(
      nf, nf1, nf2,
      (const float*)d_in[12], (const float*)d_in[13], (const float*)d_in[14], (const float*)d_in[15],
      (const float*)d_in[16], (const float*)d_in[17], (const float*)d_in[18], (const float*)d_in[19],
      (float*)d_out, N);
}